// Round 6
// baseline (384.775 us; speedup 1.0000x reference)
//
#include <hip/hip_runtime.h>
#include <math.h>

#define NT 256
#define NTG 1024
constexpr int B_   = 8192;
constexpr int N_   = 100;
constexpr int E_   = 1600;
constexpr int EMB  = 5;
constexpr int XDIM = 500;    // N_*EMB
constexpr int DDIM = 2600;   // 50*52
constexpr int XWP  = 512;    // padded x-region width ([500,512) = 0)
constexpr int DOFF = 512;    // d-region start in k' space
constexpr int KPAD = 3136;   // k' = 98 kchunks of 32
constexpr int NKC  = 98;     // kchunks per row
constexpr int H1 = 128, H2 = 128, H3 = 64, HO = 2;

typedef short short8 __attribute__((ext_vector_type(8)));
typedef float f32x4  __attribute__((ext_vector_type(4)));

__device__ __forceinline__ float leaky(float v) { return v > 0.f ? v : 0.01f * v; }
__device__ __forceinline__ float sigm(float v)  { return 1.f / (1.f + __expf(-v)); }
__device__ __forceinline__ unsigned short f2bf(float f) {   // RNE fp32->bf16
  unsigned int x = __float_as_uint(f);
  return (unsigned short)((x + 0x7fffu + ((x >> 16) & 1u)) >> 16);
}

// Fragment layout (matches mfma_f32_16x16x32_bf16 operand needs):
//   frag(R, kc)[lane][e] = M[R*16 + (lane&15)][kc*32 + (lane>>4)*8 + e]
//   linear: buf[(R*NKC + kc)*512 + lane*8 + e]   (512 shorts = 1KB per frag)
// One wave-load of a fragment = base + lane*16B -> 1KB contiguous.

// ---------------- Kernel A: fused setup (csr | prep | d->fragments) -----------
// blk 0: CSR + zero counters; blk 1..320: F1c/F2T/F3T; blk 321..3392: d->frags.
constexpr int NDT = 6;                 // col-tiles per rowblk (5 full + 1 partial)

__global__ __launch_bounds__(NT) void setup_kernel(
    const int* __restrict__ src, const int* __restrict__ dst,
    int* __restrict__ off_g, int* __restrict__ lst_g, int* __restrict__ cnt_g,
    const float* __restrict__ F1, const float* __restrict__ F2, const float* __restrict__ F3,
    unsigned short* __restrict__ F1c, unsigned short* __restrict__ F2T, unsigned short* __restrict__ F3T,
    const float* __restrict__ dmat, unsigned short* __restrict__ awf)
{
  const int blk = blockIdx.x;
  const int t   = threadIdx.x;

  if (blk == 0) {
    // ---- CSR (dst-sorted) + zero the mlp completion counters ----
    __shared__ int cnt[N_ + 1];
    __shared__ int cur[N_];
    cnt_g[t] = 0;                        // 256 row-block counters
    if (t <= N_) cnt[t] = 0;
    __syncthreads();
    for (int e = t; e < E_; e += NT) atomicAdd(&cnt[dst[e] + 1], 1);
    __syncthreads();
    if (t == 0) {
      int s = 0;
      for (int n = 0; n <= N_; ++n) { s += cnt[n]; cnt[n] = s; }
    }
    __syncthreads();
    if (t < N_) cur[t] = cnt[t];
    if (t <= N_) off_g[t] = cnt[t];
    __syncthreads();
    for (int e = t; e < E_; e += NT) {
      int d = dst[e];
      int p = atomicAdd(&cur[d], 1);
      lst_g[p] = src[e];
    }
  } else if (blk <= 320) {
    // ---- weight prep ----
    const int b = blk - 1;
    if (b < 128) {
      // F1 -> fragment-ordered F1c (col b = colblk b>>4, lane row b&15)
      for (int k = t; k < KPAD; k += NT) {
        float v = 0.f;
        if (k < XDIM)                          v = F1[(size_t)k * H1 + b];
        else if (k >= DOFF && k < DOFF + DDIM) v = F1[(size_t)(k - DOFF + XDIM) * H1 + b];
        int kc = k >> 5, q = (k >> 3) & 3, e = k & 7;
        int lane = (b & 15) + q * 16;
        F1c[((size_t)(b >> 4) * NKC + kc) * 512 + lane * 8 + e] = f2bf(v);
      }
    } else if (b < 256) {
      int n = b - 128;
      if (t < 128) F2T[n * 128 + t] = f2bf(F2[(size_t)t * H2 + n]);
    } else {
      int n = b - 256;
      if (n < 64 && t < 128) F3T[n * 128 + t] = f2bf(F3[(size_t)t * H3 + n]);
    }
  } else {
    // ---- d fp32 -> bf16 fragments: one (rowblk R, col-tile ct) per block ----
    const int idx = blk - 321;               // 0..3071
    const int R   = idx / NDT;               // 0..511 (16 rows each)
    const int ct  = idx - R * NDT;           // 0..5 (512 d-cols each; ct5 = 40)
    __shared__ __attribute__((aligned(16))) unsigned short tile[16][520];
    const float* dbase = dmat + (size_t)R * 16 * DDIM + ct * 512;

    if (ct < 5) {
      for (int i = t; i < 16 * 128; i += NT) {       // 2048 float4 loads
        int r = i >> 7, c4 = i & 127;
        float4 f = *(const float4*)(dbase + (size_t)r * DDIM + c4 * 4);
        unsigned short* tp = &tile[r][c4 * 4];       // truncate fp32->bf16
        tp[0] = (unsigned short)(__float_as_uint(f.x) >> 16);
        tp[1] = (unsigned short)(__float_as_uint(f.y) >> 16);
        tp[2] = (unsigned short)(__float_as_uint(f.z) >> 16);
        tp[3] = (unsigned short)(__float_as_uint(f.w) >> 16);
      }
      __syncthreads();
      for (int i = t; i < 16 * 64; i += NT) {        // 16 kchunks x 64 lanes
        int kcL = i >> 6, lane = i & 63;
        int r = lane & 15, q = lane >> 4;
        uint4 p = *(const uint4*)&tile[r][kcL * 32 + q * 8];
        ((uint4*)awf)[((size_t)R * NKC + 16 + ct * 16 + kcL) * 64 + lane] = p;
      }
    } else {
      for (int i = t; i < 16 * 520; i += NT) ((unsigned short*)tile)[i] = 0;
      __syncthreads();
      for (int i = t; i < 16 * 10; i += NT) {        // 40 cols = 10 float4/row
        int r = i / 10, c4 = i - r * 10;
        float4 f = *(const float4*)(dbase + (size_t)r * DDIM + c4 * 4);
        unsigned short* tp = &tile[r][c4 * 4];
        tp[0] = (unsigned short)(__float_as_uint(f.x) >> 16);
        tp[1] = (unsigned short)(__float_as_uint(f.y) >> 16);
        tp[2] = (unsigned short)(__float_as_uint(f.z) >> 16);
        tp[3] = (unsigned short)(__float_as_uint(f.w) >> 16);
      }
      __syncthreads();
      for (int i = t; i < 2 * 64; i += NT) {         // kc 96, 97 (zero-padded)
        int kcL = i >> 6, lane = i & 63;
        int r = lane & 15, q = lane >> 4;
        uint4 p = *(const uint4*)&tile[r][kcL * 32 + q * 8];
        ((uint4*)awf)[((size_t)R * NKC + 96 + kcL) * 64 + lane] = p;
      }
    }
  }
}

// ---------------- Kernel C: gated RGCN, batch-along-lanes ---------------------
constexpr int BT2 = 32;

__device__ __forceinline__ void rgcn_layer(
    const float* __restrict__ RB, float* __restrict__ WB,
    const float* __restrict__ wts, const int* __restrict__ soff,
    const int* __restrict__ sl160, int t, int wof)
{
  if (t < N_ * (BT2 / 4)) {                  // 800 items: (node, batch-quad)
    const int n  = t >> 3;
    const int b4 = (t & 7) * 4;
    f32x4 a[5];
#pragma unroll
    for (int j = 0; j < 5; ++j) a[j] = (f32x4){0.f, 0.f, 0.f, 0.f};
    const int qe = soff[n + 1];
    for (int q = soff[n]; q < qe; ++q) {
      const float* base = RB + sl160[q] + b4;
#pragma unroll
      for (int j = 0; j < 5; ++j) a[j] += *(const f32x4*)(base + j * 32);
    }
    f32x4 h2[5];
#pragma unroll
    for (int j = 0; j < 5; ++j) {
      float bb = wts[wof + 25 + j];
      f32x4 v = (f32x4){bb, bb, bb, bb};
#pragma unroll
      for (int k = 0; k < 5; ++k) v += a[k] * wts[wof + k * 5 + j];
      h2[j] = v;
    }
#pragma unroll
    for (int j = 0; j < 5; ++j) {
      float gb = wts[wof + 55 + j];
      f32x4 g = (f32x4){gb, gb, gb, gb};
#pragma unroll
      for (int k = 0; k < 5; ++k) g += h2[k] * wts[wof + 30 + k * 5 + j];
      f32x4 o;
#pragma unroll
      for (int c = 0; c < 4; ++c) o[c] = leaky(sigm(g[c]) * h2[j][c]);
      *(f32x4*)(WB + n * 160 + j * 32 + b4) = o;
    }
  }
}

__global__ __launch_bounds__(NTG) void gnn_kernel(
    const float* __restrict__ data,
    const int* __restrict__ off_g, const int* __restrict__ lst_g,
    const float* __restrict__ W0, const float* __restrict__ b0, const float* __restrict__ G0, const float* __restrict__ gb0,
    const float* __restrict__ W1, const float* __restrict__ b1, const float* __restrict__ G1, const float* __restrict__ gb1,
    const float* __restrict__ W2, const float* __restrict__ b2, const float* __restrict__ G2, const float* __restrict__ gb2,
    unsigned short* __restrict__ awf)
{
  __shared__ __attribute__((aligned(16))) float bufA[BT2 * 513];  // 65.7 KB
  __shared__ __attribute__((aligned(16))) float bufB[XDIM * BT2]; // 64 KB
  __shared__ int   soff[N_ + 1];
  __shared__ int   sl160[E_];
  __shared__ float wts[160];
  const int t   = threadIdx.x;
  const int b0_ = blockIdx.x * BT2;

  for (int i = t; i < E_; i += NTG) sl160[i] = lst_g[i] * 160;
  if (t <= N_) soff[t] = off_g[t];
  if (t < 5)  { wts[t] = W0[t]; wts[5 + t] = b0[t]; wts[35 + t] = gb0[t]; }
  if (t < 25) { wts[10 + t] = G0[t];
                wts[40 + t] = W1[t]; wts[70 + t]  = G1[t];
                wts[100 + t] = W2[t]; wts[130 + t] = G2[t]; }
  if (t < 5)  { wts[65 + t] = b1[t]; wts[95 + t]  = gb1[t];
                wts[125 + t] = b2[t]; wts[155 + t] = gb2[t]; }
  // coalesced input: 3200 contiguous floats, scatter into j=0 state slots
  for (int i = t; i < N_ * BT2; i += NTG) {
    int b = i / N_, n = i - b * N_;
    bufA[n * 160 + b] = data[(size_t)b0_ * N_ + i];
  }
  __syncthreads();

  // ---- Layer 0 (scalar input), vectorized over 4 batches/lane ----
  if (t < N_ * (BT2 / 4)) {
    const int n  = t >> 3;
    const int b4 = (t & 7) * 4;
    f32x4 a = (f32x4){0.f, 0.f, 0.f, 0.f};
    const int qe = soff[n + 1];
    for (int q = soff[n]; q < qe; ++q) a += *(const f32x4*)(bufA + sl160[q] + b4);
    f32x4 h2[5];
#pragma unroll
    for (int j = 0; j < 5; ++j) {
      float bb = wts[5 + j];
      h2[j] = a * wts[j] + (f32x4){bb, bb, bb, bb};
    }
#pragma unroll
    for (int j = 0; j < 5; ++j) {
      float gb = wts[35 + j];
      f32x4 g = (f32x4){gb, gb, gb, gb};
#pragma unroll
      for (int k = 0; k < 5; ++k) g += h2[k] * wts[10 + k * 5 + j];
      f32x4 o;
#pragma unroll
      for (int c = 0; c < 4; ++c) o[c] = leaky(sigm(g[c]) * h2[j][c]);
      *(f32x4*)(bufB + n * 160 + j * 32 + b4) = o;
    }
  }
  __syncthreads();

  rgcn_layer(bufB, bufA, wts, soff, sl160, t, 40);    // layer 1: B -> A
  __syncthreads();
  rgcn_layer(bufA, bufB, wts, soff, sl160, t, 100);   // layer 2: A -> B
  __syncthreads();

  // transpose bufB[jn][b] -> bufA[b*513 + r] (write banks (b+r)%32: conflict-free)
  for (int i = t; i < BT2 * XWP; i += NTG) {
    int b = i & 31, r = i >> 5;
    bufA[b * 513 + r] = (r < XDIM) ? bufB[r * 32 + b] : 0.f;
  }
  __syncthreads();

  // fragment-ordered store: x-region = kchunks 0..15 of rowblks R0, R0+1.
  {
    const int R0 = blockIdx.x * 2;
    for (int i = t; i < 32 * 64; i += NTG) {   // 32 frags x 64 lanes
      int f = i >> 6, lane = i & 63;
      int h = f >> 4, kc = f & 15;
      int b = h * 16 + (lane & 15);
      int k0 = kc * 32 + (lane >> 4) * 8;
      const float* sp = bufA + b * 513 + k0;
      uint4 p;
      p.x = (unsigned)f2bf(sp[0]) | ((unsigned)f2bf(sp[1]) << 16);
      p.y = (unsigned)f2bf(sp[2]) | ((unsigned)f2bf(sp[3]) << 16);
      p.z = (unsigned)f2bf(sp[4]) | ((unsigned)f2bf(sp[5]) << 16);
      p.w = (unsigned)f2bf(sp[6]) | ((unsigned)f2bf(sp[7]) << 16);
      ((uint4*)awf)[((size_t)(R0 + h) * NKC + kc) * 64 + lane] = p;
    }
  }
}

// ---------------- Kernel D: split-K MFMA GEMM1 + fused tail -------------------
// Fragment-ordered A/B: every load = 1KB lane-contiguous. MBG=32, KSPLIT=7
// (98 kchunks = 7 x 14), grid 1792 = 7 blocks/CU. Last split block per rb
// (completion counter) sums partials (L2-hot) and runs the MLP tail.
constexpr int MBG = 32;              // rows per block
constexpr int EST = 136;
constexpr int KSPLIT = 7;
constexpr int SCC = 7;               // 64k-chunks per split (7 x 2 kchunks = 14)

__global__ __launch_bounds__(NT, 4) void mlp_main(
    const unsigned short* __restrict__ awf,
    const unsigned short* __restrict__ F1c, float* __restrict__ part,
    int* __restrict__ cnt_g, const float* __restrict__ fb1,
    const unsigned short* __restrict__ F2T, const float* __restrict__ fb2,
    const unsigned short* __restrict__ F3T, const float* __restrict__ fb3,
    const float* __restrict__ F4, const float* __restrict__ fb4,
    float* __restrict__ out)
{
  __shared__ __attribute__((aligned(16))) unsigned short sH[16 * EST];
  __shared__ float sh3[16 * 68];
  __shared__ int isLast;

  const int t     = threadIdx.x;
  const int rb    = blockIdx.x & 255;          // 8192/32 = 256 row-blocks
  const int split = blockIdx.x >> 8;           // 0..6
  const int row0  = rb * MBG;
  const int lane  = t & 63;
  const int w     = t >> 6;
  const int quad  = lane >> 4;
  const int ln    = lane & 15;
  const int q8    = quad * 8;
  const int kc0   = split * (2 * SCC);         // first kchunk of this split

  const unsigned short* a0p = awf + (((size_t)(rb * 2 + 0) * NKC + kc0) * 64 + lane) * 8;
  const unsigned short* a1p = awf + (((size_t)(rb * 2 + 1) * NKC + kc0) * 64 + lane) * 8;
  const unsigned short* b0p = F1c + (((size_t)(w * 2 + 0) * NKC + kc0) * 64 + lane) * 8;
  const unsigned short* b1p = F1c + (((size_t)(w * 2 + 1) * NKC + kc0) * 64 + lane) * 8;

#define LOADF(Ax, Bx, c)                                                       \
  {                                                                            \
    _Pragma("unroll")                                                          \
    for (int s_ = 0; s_ < 2; ++s_) {                                           \
      const int o_ = (2 * (c) + s_) * 512;                                     \
      Ax[s_][0] = *(const short8*)(a0p + o_);                                  \
      Ax[s_][1] = *(const short8*)(a1p + o_);                                  \
      Bx[s_][0] = *(const short8*)(b0p + o_);                                  \
      Bx[s_][1] = *(const short8*)(b1p + o_);                                  \
    }                                                                          \
  }

  f32x4 a00 = {0.f, 0.f, 0.f, 0.f};
  f32x4 a01 = {0.f, 0.f, 0.f, 0.f};
  f32x4 a10 = {0.f, 0.f, 0.f, 0.f};
  f32x4 a11 = {0.f, 0.f, 0.f, 0.f};
  short8 A0[2][2], A1[2][2], B0[2][2], B1[2][2];

  LOADF(A0, B0, 0)
  LOADF(A1, B1, 1)
  for (int c = 0; c < SCC; ++c) {
    if (c & 1) {
#pragma unroll
      for (int s = 0; s < 2; ++s) {
        a00 = __builtin_amdgcn_mfma_f32_16x16x32_bf16(A1[s][0], B1[s][0], a00, 0, 0, 0);
        a01 = __builtin_amdgcn_mfma_f32_16x16x32_bf16(A1[s][0], B1[s][1], a01, 0, 0, 0);
        a10 = __builtin_amdgcn_mfma_f32_16x16x32_bf16(A1[s][1], B1[s][0], a10, 0, 0, 0);
        a11 = __builtin_amdgcn_mfma_f32_16x16x32_bf16(A1[s][1], B1[s][1], a11, 0, 0, 0);
      }
      if (c + 2 < SCC) LOADF(A1, B1, c + 2)
    } else {
#pragma unroll
      for (int s = 0; s < 2; ++s) {
        a00 = __builtin_amdgcn_mfma_f32_16x16x32_bf16(A0[s][0], B0[s][0], a00, 0, 0, 0);
        a01 = __builtin_amdgcn_mfma_f32_16x16x32_bf16(A0[s][0], B0[s][1], a01, 0, 0, 0);
        a10 = __builtin_amdgcn_mfma_f32_16x16x32_bf16(A0[s][1], B0[s][0], a10, 0, 0, 0);
        a11 = __builtin_amdgcn_mfma_f32_16x16x32_bf16(A0[s][1], B0[s][1], a11, 0, 0, 0);
      }
      if (c + 2 < SCC) LOADF(A0, B0, c + 2)
    }
  }
#undef LOADF

  // store partials (pre-bias): quad-contiguous 64B segments
  const int col0 = w * 32 + ln;
  float* pp = part + ((size_t)split * B_ + row0) * H1;
#pragma unroll
  for (int r = 0; r < 4; ++r) {
    int m = quad * 4 + r;
    pp[m * H1 + col0]             = a00[r];
    pp[m * H1 + col0 + 16]        = a01[r];
    pp[(m + 16) * H1 + col0]      = a10[r];
    pp[(m + 16) * H1 + col0 + 16] = a11[r];
  }

  // ---- completion counter: last split block runs the tail ----
  if (t == 0) {
    __threadfence();
    int old = atomicAdd(&cnt_g[rb], 1);
    isLast = (old == KSPLIT - 1);
  }
  __syncthreads();
  if (!isLast) return;
  __threadfence();

  constexpr size_t PS = (size_t)B_ * H1;
  for (int hs = 0; hs < 2; ++hs) {
    const int r0h = row0 + hs * 16;
    // h1 = leaky(sum partials + fb1) -> sH
    for (int i = t; i < 16 * H1; i += NT) {
      int m = i >> 7, col = i & 127;
      size_t off = (size_t)(r0h + m) * H1 + col;
      float v = fb1[col];
#pragma unroll
      for (int s = 0; s < KSPLIT; ++s) v += part[s * PS + off];
      sH[m * EST + col] = f2bf(leaky(v));
    }
    __syncthreads();

    // h2 = leaky(h1 @ F2 + fb2)
    f32x4 a20 = {0.f, 0.f, 0.f, 0.f};
    f32x4 a21 = {0.f, 0.f, 0.f, 0.f};
    {
      const unsigned short* g2a = F2T + (size_t)col0 * H2 + q8;
      const unsigned short* g2b = g2a + (size_t)16 * H2;
#pragma unroll
      for (int s = 0; s < 4; ++s) {
        short8 b0f = *(const short8*)(g2a + s * 32);
        short8 b1f = *(const short8*)(g2b + s * 32);
        short8 af  = *(const short8*)(sH + ln * EST + s * 32 + q8);
        a20 = __builtin_amdgcn_mfma_f32_16x16x32_bf16(af, b0f, a20, 0, 0, 0);
        a21 = __builtin_amdgcn_mfma_f32_16x16x32_bf16(af, b1f, a21, 0, 0, 0);
      }
    }
    __syncthreads();
    {
      float bb0 = fb2[col0], bb1 = fb2[col0 + 16];
#pragma unroll
      for (int r = 0; r < 4; ++r) {
        int m = quad * 4 + r;
        sH[m * EST + col0]      = f2bf(leaky(a20[r] + bb0));
        sH[m * EST + col0 + 16] = f2bf(leaky(a21[r] + bb1));
      }
    }
    __syncthreads();

    // h3 = leaky(h2 @ F3 + fb3): N=64
    f32x4 a3 = {0.f, 0.f, 0.f, 0.f};
    {
      const unsigned short* g3 = F3T + (size_t)(w * 16 + ln) * H2 + q8;
#pragma unroll
      for (int s = 0; s < 4; ++s) {
        short8 bf = *(const short8*)(g3 + s * 32);
        short8 af = *(const short8*)(sH + ln * EST + s * 32 + q8);
        a3 = __builtin_amdgcn_mfma_f32_16x16x32_bf16(af, bf, a3, 0, 0, 0);
      }
    }
    {
      int col = w * 16 + ln;
      float bb = fb3[col];
#pragma unroll
      for (int r = 0; r < 4; ++r)
        sh3[(quad * 4 + r) * 68 + col] = leaky(a3[r] + bb);
    }
    __syncthreads();

    // out = sigmoid(h3 @ F4 + fb4)
    if (t < 16 * HO) {
      int m = t >> 1, j = t & 1;
      float a = fb4[j];
#pragma unroll 8
      for (int k = 0; k < H3; ++k) a += sh3[m * 68 + k] * F4[k * HO + j];
      out[(size_t)(r0h + m) * HO + j] = sigm(a);
    }
    __syncthreads();
  }
}

// ---------------- launch ------------------------------------------------------
extern "C" void kernel_launch(void* const* d_in, const int* in_sizes, int n_in,
                              void* d_out, int out_size, void* d_ws, size_t ws_size,
                              hipStream_t stream) {
  const float* data = (const float*)d_in[0];
  const float* dmat = (const float*)d_in[1];
  const int*   src  = (const int*)d_in[2];
  const int*   dst  = (const int*)d_in[3];
  const float* W0 = (const float*)d_in[4];  const float* b0 = (const float*)d_in[5];
  const float* G0 = (const float*)d_in[6];  const float* gb0 = (const float*)d_in[7];
  const float* W1 = (const float*)d_in[8];  const float* b1 = (const float*)d_in[9];
  const float* G1 = (const float*)d_in[10]; const float* gb1 = (const float*)d_in[11];
  const float* W2 = (const float*)d_in[12]; const float* b2 = (const float*)d_in[13];
  const float* G2 = (const float*)d_in[14]; const float* gb2 = (const float*)d_in[15];
  const float* F1 = (const float*)d_in[16]; const float* fb1 = (const float*)d_in[17];
  const float* F2 = (const float*)d_in[18]; const float* fb2 = (const float*)d_in[19];
  const float* F3 = (const float*)d_in[20]; const float* fb3 = (const float*)d_in[21];
  const float* F4 = (const float*)d_in[22]; const float* fb4 = (const float*)d_in[23];
  float* out = (float*)d_out;

  unsigned short* awf = (unsigned short*)d_ws;          // 512*98*512 shorts (51.4 MB)
  unsigned short* F1c = awf + (size_t)B_ * KPAD;        // 8*98*512
  unsigned short* F2T = F1c + 128 * KPAD;               // 128*128
  unsigned short* F3T = F2T + 128 * 128;                // 64*128
  int* off_g = (int*)(F3T + 64 * 128);                  // 101 (pad 104)
  int* lst_g = off_g + 104;                             // 1600
  int* cnt_g = lst_g + 1600;                            // 256 counters
  float* part = (float*)(cnt_g + 256);                  // 7*8192*128 fp32 (29.4 MB)

  setup_kernel<<<1 + 320 + 512 * NDT, NT, 0, stream>>>(src, dst, off_g, lst_g, cnt_g,
                                                       F1, F2, F3, F1c, F2T, F3T,
                                                       dmat, awf);
  gnn_kernel<<<B_ / BT2, NTG, 0, stream>>>(data, off_g, lst_g,
                                           W0, b0, G0, gb0,
                                           W1, b1, G1, gb1,
                                           W2, b2, G2, gb2, awf);
  mlp_main<<<(B_ / MBG) * KSPLIT, NT, 0, stream>>>(awf, F1c, part, cnt_g,
                                                   fb1, F2T, fb2,
                                                   F3T, fb3, F4, fb4, out);
}

// Round 7
// 241.268 us; speedup vs baseline: 1.5948x; 1.5948x over previous
//
#include <hip/hip_runtime.h>
#include <math.h>

#define NT 256
constexpr int B_   = 8192;
constexpr int N_   = 100;
constexpr int E_   = 1600;
constexpr int EMB  = 5;
constexpr int XDIM = 500;    // N_*EMB
constexpr int DDIM = 2600;   // 50*52
constexpr int XWP  = 512;    // padded x-region width ([500,512) = 0)
constexpr int DOFF = 512;    // d-region start in k' space
constexpr int KPAD = 3136;   // k' = 98 kchunks of 32
constexpr int NKC  = 98;     // kchunks per row
constexpr int H1 = 128, H2 = 128, H3 = 64, HO = 2;

typedef short short8 __attribute__((ext_vector_type(8)));
typedef float f32x4  __attribute__((ext_vector_type(4)));

__device__ __forceinline__ float leaky(float v) { return v > 0.f ? v : 0.01f * v; }
__device__ __forceinline__ float sigm(float v)  { return 1.f / (1.f + __expf(-v)); }
__device__ __forceinline__ unsigned short f2bf(float f) {   // RNE fp32->bf16
  unsigned int x = __float_as_uint(f);
  return (unsigned short)((x + 0x7fffu + ((x >> 16) & 1u)) >> 16);
}

// Fragment layout (matches mfma_f32_16x16x32_bf16 operand needs):
//   frag(R, kc)[lane][e] = M[R*16 + (lane&15)][kc*32 + (lane>>4)*8 + e]
//   linear: buf[(R*NKC + kc)*512 + lane*8 + e]   (512 shorts = 1KB per frag)
// One wave-load of a fragment = base + lane*16B -> 1KB contiguous.

// ---------------- Kernel A: fused setup (csr | prep | d->fragments) -----------
// blk 0: CSR; blk 1..320: F1c/F2T/F3T; blk 321..3392: d fp32 -> bf16 fragments,
// one block per (rowblk R, col-tile ct) for max occupancy (3072 d-blocks).
constexpr int NDT = 6;                 // col-tiles per rowblk (5 full + 1 partial)

__global__ __launch_bounds__(NT) void setup_kernel(
    const int* __restrict__ src, const int* __restrict__ dst,
    int* __restrict__ off_g, int* __restrict__ lst_g,
    const float* __restrict__ F1, const float* __restrict__ F2, const float* __restrict__ F3,
    unsigned short* __restrict__ F1c, unsigned short* __restrict__ F2T, unsigned short* __restrict__ F3T,
    const float* __restrict__ dmat, unsigned short* __restrict__ awf)
{
  const int blk = blockIdx.x;
  const int t   = threadIdx.x;

  if (blk == 0) {
    // ---- CSR (dst-sorted) ----
    __shared__ int cnt[N_ + 1];
    __shared__ int cur[N_];
    if (t <= N_) cnt[t] = 0;
    __syncthreads();
    for (int e = t; e < E_; e += NT) atomicAdd(&cnt[dst[e] + 1], 1);
    __syncthreads();
    if (t == 0) {
      int s = 0;
      for (int n = 0; n <= N_; ++n) { s += cnt[n]; cnt[n] = s; }
    }
    __syncthreads();
    if (t < N_) cur[t] = cnt[t];
    if (t <= N_) off_g[t] = cnt[t];
    __syncthreads();
    for (int e = t; e < E_; e += NT) {
      int d = dst[e];
      int p = atomicAdd(&cur[d], 1);
      lst_g[p] = src[e];
    }
  } else if (blk <= 320) {
    // ---- weight prep ----
    const int b = blk - 1;
    if (b < 128) {
      // F1 -> fragment-ordered F1c (col b = colblk b>>4, lane row b&15)
      for (int k = t; k < KPAD; k += NT) {
        float v = 0.f;
        if (k < XDIM)                          v = F1[(size_t)k * H1 + b];
        else if (k >= DOFF && k < DOFF + DDIM) v = F1[(size_t)(k - DOFF + XDIM) * H1 + b];
        int kc = k >> 5, q = (k >> 3) & 3, e = k & 7;
        int lane = (b & 15) + q * 16;
        F1c[((size_t)(b >> 4) * NKC + kc) * 512 + lane * 8 + e] = f2bf(v);
      }
    } else if (b < 256) {
      int n = b - 128;
      if (t < 128) F2T[n * 128 + t] = f2bf(F2[(size_t)t * H2 + n]);
    } else {
      int n = b - 256;
      if (n < 64 && t < 128) F3T[n * 128 + t] = f2bf(F3[(size_t)t * H3 + n]);
    }
  } else {
    // ---- d fp32 -> bf16 fragments: one (rowblk R, col-tile ct) per block ----
    const int idx = blk - 321;               // 0..3071
    const int R   = idx / NDT;               // 0..511 (16 rows each)
    const int ct  = idx - R * NDT;           // 0..5 (512 d-cols each; ct5 = 40)
    __shared__ __attribute__((aligned(16))) unsigned short tile[16][520];
    const float* dbase = dmat + (size_t)R * 16 * DDIM + ct * 512;

    if (ct < 5) {
      for (int i = t; i < 16 * 128; i += NT) {       // 2048 float4 loads
        int r = i >> 7, c4 = i & 127;
        float4 f = *(const float4*)(dbase + (size_t)r * DDIM + c4 * 4);
        unsigned short* tp = &tile[r][c4 * 4];       // truncate fp32->bf16
        tp[0] = (unsigned short)(__float_as_uint(f.x) >> 16);
        tp[1] = (unsigned short)(__float_as_uint(f.y) >> 16);
        tp[2] = (unsigned short)(__float_as_uint(f.z) >> 16);
        tp[3] = (unsigned short)(__float_as_uint(f.w) >> 16);
      }
      __syncthreads();
      for (int i = t; i < 16 * 64; i += NT) {        // 16 kchunks x 64 lanes
        int kcL = i >> 6, lane = i & 63;
        int r = lane & 15, q = lane >> 4;
        uint4 p = *(const uint4*)&tile[r][kcL * 32 + q * 8];
        ((uint4*)awf)[((size_t)R * NKC + 16 + ct * 16 + kcL) * 64 + lane] = p;
      }
    } else {
      for (int i = t; i < 16 * 520; i += NT) ((unsigned short*)tile)[i] = 0;
      __syncthreads();
      for (int i = t; i < 16 * 10; i += NT) {        // 40 cols = 10 float4/row
        int r = i / 10, c4 = i - r * 10;
        float4 f = *(const float4*)(dbase + (size_t)r * DDIM + c4 * 4);
        unsigned short* tp = &tile[r][c4 * 4];
        tp[0] = (unsigned short)(__float_as_uint(f.x) >> 16);
        tp[1] = (unsigned short)(__float_as_uint(f.y) >> 16);
        tp[2] = (unsigned short)(__float_as_uint(f.z) >> 16);
        tp[3] = (unsigned short)(__float_as_uint(f.w) >> 16);
      }
      __syncthreads();
      for (int i = t; i < 2 * 64; i += NT) {         // kc 96, 97 (zero-padded)
        int kcL = i >> 6, lane = i & 63;
        int r = lane & 15, q = lane >> 4;
        uint4 p = *(const uint4*)&tile[r][kcL * 32 + q * 8];
        ((uint4*)awf)[((size_t)R * NKC + 96 + kcL) * 64 + lane] = p;
      }
    }
  }
}

// ---------------- Kernel C: gated RGCN, batch-along-lanes ---------------------
// BTG=16 batches/block, 512 threads, 72 KB LDS -> 2 blocks/CU (barrier overlap).
// State layout [jn=n*5+j][b] stride 16; each lane owns 4 batches (f32x4 reads).
constexpr int BTG  = 16;
constexpr int NTG2 = 512;

__device__ __forceinline__ void rgcn_layer16(
    const float* __restrict__ RB, float* __restrict__ WB,
    const float* __restrict__ wts, const int* __restrict__ soff,
    const int* __restrict__ sl80, int t, int wof)
{
  if (t < N_ * (BTG / 4)) {                  // 400 items: (node, batch-quad)
    const int n  = t >> 2;
    const int b4 = (t & 3) * 4;
    f32x4 a[5];
#pragma unroll
    for (int j = 0; j < 5; ++j) a[j] = (f32x4){0.f, 0.f, 0.f, 0.f};
    const int qe = soff[n + 1];
    for (int q = soff[n]; q < qe; ++q) {
      const float* base = RB + sl80[q] + b4;
#pragma unroll
      for (int j = 0; j < 5; ++j) a[j] += *(const f32x4*)(base + j * 16);
    }
    f32x4 h2[5];
#pragma unroll
    for (int j = 0; j < 5; ++j) {
      float bb = wts[wof + 25 + j];
      f32x4 v = (f32x4){bb, bb, bb, bb};
#pragma unroll
      for (int k = 0; k < 5; ++k) v += a[k] * wts[wof + k * 5 + j];
      h2[j] = v;
    }
#pragma unroll
    for (int j = 0; j < 5; ++j) {
      float gb = wts[wof + 55 + j];
      f32x4 g = (f32x4){gb, gb, gb, gb};
#pragma unroll
      for (int k = 0; k < 5; ++k) g += h2[k] * wts[wof + 30 + k * 5 + j];
      f32x4 o;
#pragma unroll
      for (int c = 0; c < 4; ++c) o[c] = leaky(sigm(g[c]) * h2[j][c]);
      *(f32x4*)(WB + n * 80 + j * 16 + b4) = o;
    }
  }
}

__global__ __launch_bounds__(NTG2) void gnn_kernel(
    const float* __restrict__ data,
    const int* __restrict__ off_g, const int* __restrict__ lst_g,
    const float* __restrict__ W0, const float* __restrict__ b0, const float* __restrict__ G0, const float* __restrict__ gb0,
    const float* __restrict__ W1, const float* __restrict__ b1, const float* __restrict__ G1, const float* __restrict__ gb1,
    const float* __restrict__ W2, const float* __restrict__ b2, const float* __restrict__ G2, const float* __restrict__ gb2,
    unsigned short* __restrict__ awf)
{
  __shared__ __attribute__((aligned(16))) float bufA[BTG * 513];  // 32.8 KB
  __shared__ __attribute__((aligned(16))) float bufB[XDIM * BTG]; // 32 KB
  __shared__ int   soff[N_ + 1];
  __shared__ int   sl80[E_];
  __shared__ float wts[160];
  const int t   = threadIdx.x;
  const int b0_ = blockIdx.x * BTG;

  for (int i = t; i < E_; i += NTG2) sl80[i] = lst_g[i] * 80;
  if (t <= N_) soff[t] = off_g[t];
  if (t < 5)  { wts[t] = W0[t]; wts[5 + t] = b0[t]; wts[35 + t] = gb0[t]; }
  if (t < 25) { wts[10 + t] = G0[t];
                wts[40 + t] = W1[t]; wts[70 + t]  = G1[t];
                wts[100 + t] = W2[t]; wts[130 + t] = G2[t]; }
  if (t < 5)  { wts[65 + t] = b1[t]; wts[95 + t]  = gb1[t];
                wts[125 + t] = b2[t]; wts[155 + t] = gb2[t]; }
  // coalesced input: 1600 contiguous floats, scatter into j=0 state slots
  for (int i = t; i < N_ * BTG; i += NTG2) {
    int b = i / N_, n = i - b * N_;
    bufA[n * 80 + b] = data[(size_t)b0_ * N_ + i];
  }
  __syncthreads();

  // ---- Layer 0 (scalar input), vectorized over 4 batches/lane ----
  if (t < N_ * (BTG / 4)) {                  // 400
    const int n  = t >> 2;
    const int b4 = (t & 3) * 4;
    f32x4 a = (f32x4){0.f, 0.f, 0.f, 0.f};
    const int qe = soff[n + 1];
    for (int q = soff[n]; q < qe; ++q) a += *(const f32x4*)(bufA + sl80[q] + b4);
    f32x4 h2[5];
#pragma unroll
    for (int j = 0; j < 5; ++j) {
      float bb = wts[5 + j];
      h2[j] = a * wts[j] + (f32x4){bb, bb, bb, bb};
    }
#pragma unroll
    for (int j = 0; j < 5; ++j) {
      float gb = wts[35 + j];
      f32x4 g = (f32x4){gb, gb, gb, gb};
#pragma unroll
      for (int k = 0; k < 5; ++k) g += h2[k] * wts[10 + k * 5 + j];
      f32x4 o;
#pragma unroll
      for (int c = 0; c < 4; ++c) o[c] = leaky(sigm(g[c]) * h2[j][c]);
      *(f32x4*)(bufB + n * 80 + j * 16 + b4) = o;
    }
  }
  __syncthreads();

  rgcn_layer16(bufB, bufA, wts, soff, sl80, t, 40);    // layer 1: B -> A
  __syncthreads();
  rgcn_layer16(bufA, bufB, wts, soff, sl80, t, 100);   // layer 2: A -> B
  __syncthreads();

  // transpose bufB[jn][b] -> bufA[b*513 + r]
  for (int i = t; i < BTG * XWP; i += NTG2) {   // 16*512 = 8192
    int b = i & 15, r = i >> 4;
    bufA[b * 513 + r] = (r < XDIM) ? bufB[r * 16 + b] : 0.f;
  }
  __syncthreads();

  // fragment-ordered store: x-region = kchunks 0..15 of rowblk R = blockIdx.x
  {
    const int R = blockIdx.x;
    for (int i = t; i < 16 * 64; i += NTG2) {   // 16 frags x 64 lanes
      int kc = i >> 6, lane = i & 63;
      int b  = lane & 15;
      int k0 = kc * 32 + (lane >> 4) * 8;
      const float* sp = bufA + b * 513 + k0;
      uint4 p;
      p.x = (unsigned)f2bf(sp[0]) | ((unsigned)f2bf(sp[1]) << 16);
      p.y = (unsigned)f2bf(sp[2]) | ((unsigned)f2bf(sp[3]) << 16);
      p.z = (unsigned)f2bf(sp[4]) | ((unsigned)f2bf(sp[5]) << 16);
      p.w = (unsigned)f2bf(sp[6]) | ((unsigned)f2bf(sp[7]) << 16);
      ((uint4*)awf)[((size_t)R * NKC + kc) * 64 + lane] = p;
    }
  }
}

// ---------------- Kernel D: split-K streaming MFMA GEMM1 ----------------------
// Fragment-ordered A/B: every load = 1KB lane-contiguous. MBG=32, KSPLIT=7
// (98 kchunks = 7 x 14), grid 1792 = 7 blocks/CU.
constexpr int MBG = 32;              // mlp_main rows per block
constexpr int MB2 = 16;              // tail_kernel rows per block
constexpr int EST = 136;
constexpr int KSPLIT = 7;
constexpr int SCC = 7;               // 64k-chunks per split (7 x 2 kchunks = 14)

__global__ __launch_bounds__(NT, 4) void mlp_main(
    const unsigned short* __restrict__ awf,
    const unsigned short* __restrict__ F1c, float* __restrict__ part)
{
  const int t     = threadIdx.x;
  const int rb    = blockIdx.x & 255;          // 8192/32 = 256 row-blocks
  const int split = blockIdx.x >> 8;           // 0..6
  const int row0  = rb * MBG;
  const int lane  = t & 63;
  const int w     = t >> 6;
  const int quad  = lane >> 4;
  const int ln    = lane & 15;
  const int kc0   = split * (2 * SCC);         // first kchunk of this split

  const unsigned short* a0p = awf + (((size_t)(rb * 2 + 0) * NKC + kc0) * 64 + lane) * 8;
  const unsigned short* a1p = awf + (((size_t)(rb * 2 + 1) * NKC + kc0) * 64 + lane) * 8;
  const unsigned short* b0p = F1c + (((size_t)(w * 2 + 0) * NKC + kc0) * 64 + lane) * 8;
  const unsigned short* b1p = F1c + (((size_t)(w * 2 + 1) * NKC + kc0) * 64 + lane) * 8;

#define LOADF(Ax, Bx, c)                                                       \
  {                                                                            \
    _Pragma("unroll")                                                          \
    for (int s_ = 0; s_ < 2; ++s_) {                                           \
      const int o_ = (2 * (c) + s_) * 512;                                     \
      Ax[s_][0] = *(const short8*)(a0p + o_);                                  \
      Ax[s_][1] = *(const short8*)(a1p + o_);                                  \
      Bx[s_][0] = *(const short8*)(b0p + o_);                                  \
      Bx[s_][1] = *(const short8*)(b1p + o_);                                  \
    }                                                                          \
  }

  f32x4 a00 = {0.f, 0.f, 0.f, 0.f};
  f32x4 a01 = {0.f, 0.f, 0.f, 0.f};
  f32x4 a10 = {0.f, 0.f, 0.f, 0.f};
  f32x4 a11 = {0.f, 0.f, 0.f, 0.f};
  short8 A0[2][2], A1[2][2], B0[2][2], B1[2][2];

  LOADF(A0, B0, 0)
  LOADF(A1, B1, 1)
  for (int c = 0; c < SCC; ++c) {
    if (c & 1) {
#pragma unroll
      for (int s = 0; s < 2; ++s) {
        a00 = __builtin_amdgcn_mfma_f32_16x16x32_bf16(A1[s][0], B1[s][0], a00, 0, 0, 0);
        a01 = __builtin_amdgcn_mfma_f32_16x16x32_bf16(A1[s][0], B1[s][1], a01, 0, 0, 0);
        a10 = __builtin_amdgcn_mfma_f32_16x16x32_bf16(A1[s][1], B1[s][0], a10, 0, 0, 0);
        a11 = __builtin_amdgcn_mfma_f32_16x16x32_bf16(A1[s][1], B1[s][1], a11, 0, 0, 0);
      }
      if (c + 2 < SCC) LOADF(A1, B1, c + 2)
    } else {
#pragma unroll
      for (int s = 0; s < 2; ++s) {
        a00 = __builtin_amdgcn_mfma_f32_16x16x32_bf16(A0[s][0], B0[s][0], a00, 0, 0, 0);
        a01 = __builtin_amdgcn_mfma_f32_16x16x32_bf16(A0[s][0], B0[s][1], a01, 0, 0, 0);
        a10 = __builtin_amdgcn_mfma_f32_16x16x32_bf16(A0[s][1], B0[s][0], a10, 0, 0, 0);
        a11 = __builtin_amdgcn_mfma_f32_16x16x32_bf16(A0[s][1], B0[s][1], a11, 0, 0, 0);
      }
      if (c + 2 < SCC) LOADF(A0, B0, c + 2)
    }
  }
#undef LOADF

  // store partials (pre-bias): quad-contiguous 64B segments
  const int col0 = w * 32 + ln;
  float* pp = part + ((size_t)split * B_ + row0) * H1;
#pragma unroll
  for (int r = 0; r < 4; ++r) {
    int m = quad * 4 + r;
    pp[m * H1 + col0]             = a00[r];
    pp[m * H1 + col0 + 16]        = a01[r];
    pp[(m + 16) * H1 + col0]      = a10[r];
    pp[(m + 16) * H1 + col0 + 16] = a11[r];
  }
}

// ---------------- Kernel E: partial-sum + fused MLP tail ----------------------
__global__ __launch_bounds__(NT) void tail_kernel(
    const float* __restrict__ part, const float* __restrict__ fb1,
    const unsigned short* __restrict__ F2T, const float* __restrict__ fb2,
    const unsigned short* __restrict__ F3T, const float* __restrict__ fb3,
    const float* __restrict__ F4, const float* __restrict__ fb4,
    float* __restrict__ out)
{
  __shared__ __attribute__((aligned(16))) unsigned short sH[MB2 * EST];
  __shared__ float sh3[MB2 * 68];

  const int t    = threadIdx.x;
  const int row0 = blockIdx.x * MB2;
  const int lane = t & 63;
  const int w    = t >> 6;
  const int quad = lane >> 4;
  const int ln   = lane & 15;
  const int q8   = quad * 8;
  constexpr size_t PS = (size_t)B_ * H1;

  // h1 = leaky(sum partials + fb1) -> sH
  for (int i = t; i < MB2 * H1; i += NT) {
    int m = i >> 7, col = i & 127;
    size_t off = (size_t)(row0 + m) * H1 + col;
    float v = fb1[col];
#pragma unroll
    for (int s = 0; s < KSPLIT; ++s) v += part[s * PS + off];
    sH[m * EST + col] = f2bf(leaky(v));
  }
  __syncthreads();

  const int col0 = w * 32 + ln;
  // h2 = leaky(h1 @ F2 + fb2)
  f32x4 a20 = {0.f, 0.f, 0.f, 0.f};
  f32x4 a21 = {0.f, 0.f, 0.f, 0.f};
  {
    const unsigned short* g2a = F2T + (size_t)col0 * H2 + q8;
    const unsigned short* g2b = g2a + (size_t)16 * H2;
#pragma unroll
    for (int s = 0; s < 4; ++s) {
      short8 b0f = *(const short8*)(g2a + s * 32);
      short8 b1f = *(const short8*)(g2b + s * 32);
      short8 af  = *(const short8*)(sH + ln * EST + s * 32 + q8);
      a20 = __builtin_amdgcn_mfma_f32_16x16x32_bf16(af, b0f, a20, 0, 0, 0);
      a21 = __builtin_amdgcn_mfma_f32_16x16x32_bf16(af, b1f, a21, 0, 0, 0);
    }
  }
  __syncthreads();
  {
    float bb0 = fb2[col0], bb1 = fb2[col0 + 16];
#pragma unroll
    for (int r = 0; r < 4; ++r) {
      int m = quad * 4 + r;
      sH[m * EST + col0]      = f2bf(leaky(a20[r] + bb0));
      sH[m * EST + col0 + 16] = f2bf(leaky(a21[r] + bb1));
    }
  }
  __syncthreads();

  // h3 = leaky(h2 @ F3 + fb3): N=64
  f32x4 a3 = {0.f, 0.f, 0.f, 0.f};
  {
    const unsigned short* g3 = F3T + (size_t)(w * 16 + ln) * H2 + q8;
#pragma unroll
    for (int s = 0; s < 4; ++s) {
      short8 bf = *(const short8*)(g3 + s * 32);
      short8 af = *(const short8*)(sH + ln * EST + s * 32 + q8);
      a3 = __builtin_amdgcn_mfma_f32_16x16x32_bf16(af, bf, a3, 0, 0, 0);
    }
  }
  {
    int col = w * 16 + ln;
    float bb = fb3[col];
#pragma unroll
    for (int r = 0; r < 4; ++r)
      sh3[(quad * 4 + r) * 68 + col] = leaky(a3[r] + bb);
  }
  __syncthreads();

  // out = sigmoid(h3 @ F4 + fb4)
  if (t < MB2 * HO) {
    int m = t >> 1, j = t & 1;
    float a = fb4[j];
#pragma unroll 8
    for (int k = 0; k < H3; ++k) a += sh3[m * 68 + k] * F4[k * HO + j];
    out[(size_t)(row0 + m) * HO + j] = sigm(a);
  }
}

// ---------------- launch ------------------------------------------------------
extern "C" void kernel_launch(void* const* d_in, const int* in_sizes, int n_in,
                              void* d_out, int out_size, void* d_ws, size_t ws_size,
                              hipStream_t stream) {
  const float* data = (const float*)d_in[0];
  const float* dmat = (const float*)d_in[1];
  const int*   src  = (const int*)d_in[2];
  const int*   dst  = (const int*)d_in[3];
  const float* W0 = (const float*)d_in[4];  const float* b0 = (const float*)d_in[5];
  const float* G0 = (const float*)d_in[6];  const float* gb0 = (const float*)d_in[7];
  const float* W1 = (const float*)d_in[8];  const float* b1 = (const float*)d_in[9];
  const float* G1 = (const float*)d_in[10]; const float* gb1 = (const float*)d_in[11];
  const float* W2 = (const float*)d_in[12]; const float* b2 = (const float*)d_in[13];
  const float* G2 = (const float*)d_in[14]; const float* gb2 = (const float*)d_in[15];
  const float* F1 = (const float*)d_in[16]; const float* fb1 = (const float*)d_in[17];
  const float* F2 = (const float*)d_in[18]; const float* fb2 = (const float*)d_in[19];
  const float* F3 = (const float*)d_in[20]; const float* fb3 = (const float*)d_in[21];
  const float* F4 = (const float*)d_in[22]; const float* fb4 = (const float*)d_in[23];
  float* out = (float*)d_out;

  unsigned short* awf = (unsigned short*)d_ws;          // 512*98*512 shorts (51.4 MB)
  unsigned short* F1c = awf + (size_t)B_ * KPAD;        // 8*98*512
  unsigned short* F2T = F1c + 128 * KPAD;               // 128*128
  unsigned short* F3T = F2T + 128 * 128;                // 64*128
  int* off_g = (int*)(F3T + 64 * 128);                  // 101 (pad 104)
  int* lst_g = off_g + 104;                             // 1600
  float* part = (float*)(lst_g + 1600);                 // 7*8192*128 fp32 (29.4 MB)

  setup_kernel<<<1 + 320 + 512 * NDT, NT, 0, stream>>>(src, dst, off_g, lst_g,
                                                       F1, F2, F3, F1c, F2T, F3T,
                                                       dmat, awf);
  gnn_kernel<<<B_ / BTG, NTG2, 0, stream>>>(data, off_g, lst_g,
                                            W0, b0, G0, gb0,
                                            W1, b1, G1, gb1,
                                            W2, b2, G2, gb2, awf);
  mlp_main<<<(B_ / MBG) * KSPLIT, NT, 0, stream>>>(awf, F1c, part);
  tail_kernel<<<B_ / MB2, NT, 0, stream>>>(part, fb1, F2T, fb2,
                                           F3T, fb3, F4, fb4, out);
}

// Round 8
// 235.839 us; speedup vs baseline: 1.6315x; 1.0230x over previous
//
#include <hip/hip_runtime.h>
#include <math.h>

#define NT 256
#define NTG 1024
constexpr int B_   = 8192;
constexpr int N_   = 100;
constexpr int E_   = 1600;
constexpr int EMB  = 5;
constexpr int XDIM = 500;    // N_*EMB
constexpr int DDIM = 2600;   // 50*52
constexpr int XWP  = 512;    // padded x-region width ([500,512) = 0)
constexpr int DOFF = 512;    // d-region start in k' space
constexpr int KPAD = 3136;   // k' = 98 kchunks of 32
constexpr int NKC  = 98;     // kchunks per row
constexpr int H1 = 128, H2 = 128, H3 = 64, HO = 2;

typedef short short8 __attribute__((ext_vector_type(8)));
typedef float f32x4  __attribute__((ext_vector_type(4)));

__device__ __forceinline__ float leaky(float v) { return v > 0.f ? v : 0.01f * v; }
__device__ __forceinline__ float sigm(float v)  { return 1.f / (1.f + __expf(-v)); }
__device__ __forceinline__ unsigned short f2bf(float f) {   // RNE fp32->bf16
  unsigned int x = __float_as_uint(f);
  return (unsigned short)((x + 0x7fffu + ((x >> 16) & 1u)) >> 16);
}

// Fragment layout (matches mfma_f32_16x16x32_bf16 operand needs):
//   frag(R, kc)[lane][e] = M[R*16 + (lane&15)][kc*32 + (lane>>4)*8 + e]
//   linear: buf[(R*NKC + kc)*512 + lane*8 + e]   (512 shorts = 1KB per frag)

// ---------------- Kernel A: fused setup (csr | prep | d->fragments) -----------
// blk 0: CSR + degree-sort perm; blk 1..320: F1c/F2T/F3T; blk 321..3392: d->frags.
constexpr int NDT = 6;                 // col-tiles per rowblk (5 full + 1 partial)

__global__ __launch_bounds__(NT) void setup_kernel(
    const int* __restrict__ src, const int* __restrict__ dst,
    int* __restrict__ off_g, int* __restrict__ lst_g, int* __restrict__ perm_g,
    const float* __restrict__ F1, const float* __restrict__ F2, const float* __restrict__ F3,
    unsigned short* __restrict__ F1c, unsigned short* __restrict__ F2T, unsigned short* __restrict__ F3T,
    const float* __restrict__ dmat, unsigned short* __restrict__ awf)
{
  const int blk = blockIdx.x;
  const int t   = threadIdx.x;

  if (blk == 0) {
    // ---- CSR (dst-sorted) + degree-descending node permutation ----
    __shared__ int cnt[N_ + 1];
    __shared__ int cur[N_];
    if (t <= N_) cnt[t] = 0;
    __syncthreads();
    for (int e = t; e < E_; e += NT) atomicAdd(&cnt[dst[e] + 1], 1);
    __syncthreads();
    if (t == 0) {
      int s = 0;
      for (int n = 0; n <= N_; ++n) { s += cnt[n]; cnt[n] = s; }
    }
    __syncthreads();
    if (t < N_) cur[t] = cnt[t];
    if (t <= N_) off_g[t] = cnt[t];
    // rank nodes by degree (desc, stable): similar-degree nodes share a wave
    if (t < N_) {
      int dn = cnt[t + 1] - cnt[t];
      int r = 0;
      for (int m = 0; m < N_; ++m) {
        int dm = cnt[m + 1] - cnt[m];
        r += (dm > dn) || (dm == dn && m < t);
      }
      perm_g[r] = t;
    }
    __syncthreads();
    for (int e = t; e < E_; e += NT) {
      int d = dst[e];
      int p = atomicAdd(&cur[d], 1);
      lst_g[p] = src[e];
    }
  } else if (blk <= 320) {
    // ---- weight prep ----
    const int b = blk - 1;
    if (b < 128) {
      for (int k = t; k < KPAD; k += NT) {
        float v = 0.f;
        if (k < XDIM)                          v = F1[(size_t)k * H1 + b];
        else if (k >= DOFF && k < DOFF + DDIM) v = F1[(size_t)(k - DOFF + XDIM) * H1 + b];
        int kc = k >> 5, q = (k >> 3) & 3, e = k & 7;
        int lane = (b & 15) + q * 16;
        F1c[((size_t)(b >> 4) * NKC + kc) * 512 + lane * 8 + e] = f2bf(v);
      }
    } else if (b < 256) {
      int n = b - 128;
      if (t < 128) F2T[n * 128 + t] = f2bf(F2[(size_t)t * H2 + n]);
    } else {
      int n = b - 256;
      if (n < 64 && t < 128) F3T[n * 128 + t] = f2bf(F3[(size_t)t * H3 + n]);
    }
  } else {
    // ---- d fp32 -> bf16 fragments: one (rowblk R, col-tile ct) per block ----
    const int idx = blk - 321;               // 0..3071
    const int R   = idx / NDT;               // 0..511 (16 rows each)
    const int ct  = idx - R * NDT;           // 0..5 (512 d-cols each; ct5 = 40)
    __shared__ __attribute__((aligned(16))) unsigned short tile[16][520];
    const float* dbase = dmat + (size_t)R * 16 * DDIM + ct * 512;

    if (ct < 5) {
      for (int i = t; i < 16 * 128; i += NT) {       // 2048 float4 loads
        int r = i >> 7, c4 = i & 127;
        float4 f = *(const float4*)(dbase + (size_t)r * DDIM + c4 * 4);
        unsigned short* tp = &tile[r][c4 * 4];       // truncate fp32->bf16
        tp[0] = (unsigned short)(__float_as_uint(f.x) >> 16);
        tp[1] = (unsigned short)(__float_as_uint(f.y) >> 16);
        tp[2] = (unsigned short)(__float_as_uint(f.z) >> 16);
        tp[3] = (unsigned short)(__float_as_uint(f.w) >> 16);
      }
      __syncthreads();
      for (int i = t; i < 16 * 64; i += NT) {        // 16 kchunks x 64 lanes
        int kcL = i >> 6, lane = i & 63;
        int r = lane & 15, q = lane >> 4;
        uint4 p = *(const uint4*)&tile[r][kcL * 32 + q * 8];
        ((uint4*)awf)[((size_t)R * NKC + 16 + ct * 16 + kcL) * 64 + lane] = p;
      }
    } else {
      for (int i = t; i < 16 * 520; i += NT) ((unsigned short*)tile)[i] = 0;
      __syncthreads();
      for (int i = t; i < 16 * 10; i += NT) {        // 40 cols = 10 float4/row
        int r = i / 10, c4 = i - r * 10;
        float4 f = *(const float4*)(dbase + (size_t)r * DDIM + c4 * 4);
        unsigned short* tp = &tile[r][c4 * 4];
        tp[0] = (unsigned short)(__float_as_uint(f.x) >> 16);
        tp[1] = (unsigned short)(__float_as_uint(f.y) >> 16);
        tp[2] = (unsigned short)(__float_as_uint(f.z) >> 16);
        tp[3] = (unsigned short)(__float_as_uint(f.w) >> 16);
      }
      __syncthreads();
      for (int i = t; i < 2 * 64; i += NT) {         // kc 96, 97 (zero-padded)
        int kcL = i >> 6, lane = i & 63;
        int r = lane & 15, q = lane >> 4;
        uint4 p = *(const uint4*)&tile[r][kcL * 32 + q * 8];
        ((uint4*)awf)[((size_t)R * NKC + 96 + kcL) * 64 + lane] = p;
      }
    }
  }
}

// ---------------- Kernel C: gated RGCN, batch-along-lanes ---------------------
// BT2=32 batches/block, 1024 threads, stride-160 state (bank-balanced gathers).
// Nodes processed in degree-sorted order (sperm) to cut wave divergence.
constexpr int BT2 = 32;

__device__ __forceinline__ void rgcn_layer(
    const float* __restrict__ RB, float* __restrict__ WB,
    const float* __restrict__ wts, const int* __restrict__ soff,
    const int* __restrict__ sl160, const int* __restrict__ sperm,
    int t, int wof)
{
  if (t < N_ * (BT2 / 4)) {                  // 800 items: (node-slot, batch-quad)
    const int nn = sperm[t >> 3];
    const int b4 = (t & 7) * 4;
    f32x4 a[5];
#pragma unroll
    for (int j = 0; j < 5; ++j) a[j] = (f32x4){0.f, 0.f, 0.f, 0.f};
    const int qe = soff[nn + 1];
    for (int q = soff[nn]; q < qe; ++q) {
      const float* base = RB + sl160[q] + b4;
#pragma unroll
      for (int j = 0; j < 5; ++j) a[j] += *(const f32x4*)(base + j * 32);
    }
    f32x4 h2[5];
#pragma unroll
    for (int j = 0; j < 5; ++j) {
      float bb = wts[wof + 25 + j];
      f32x4 v = (f32x4){bb, bb, bb, bb};
#pragma unroll
      for (int k = 0; k < 5; ++k) v += a[k] * wts[wof + k * 5 + j];
      h2[j] = v;
    }
#pragma unroll
    for (int j = 0; j < 5; ++j) {
      float gb = wts[wof + 55 + j];
      f32x4 g = (f32x4){gb, gb, gb, gb};
#pragma unroll
      for (int k = 0; k < 5; ++k) g += h2[k] * wts[wof + 30 + k * 5 + j];
      f32x4 o;
#pragma unroll
      for (int c = 0; c < 4; ++c) o[c] = leaky(sigm(g[c]) * h2[j][c]);
      *(f32x4*)(WB + nn * 160 + j * 32 + b4) = o;
    }
  }
}

__global__ __launch_bounds__(NTG) void gnn_kernel(
    const float* __restrict__ data,
    const int* __restrict__ off_g, const int* __restrict__ lst_g, const int* __restrict__ perm_g,
    const float* __restrict__ W0, const float* __restrict__ b0, const float* __restrict__ G0, const float* __restrict__ gb0,
    const float* __restrict__ W1, const float* __restrict__ b1, const float* __restrict__ G1, const float* __restrict__ gb1,
    const float* __restrict__ W2, const float* __restrict__ b2, const float* __restrict__ G2, const float* __restrict__ gb2,
    unsigned short* __restrict__ awf)
{
  __shared__ __attribute__((aligned(16))) float bufA[BT2 * 513];  // 65.7 KB
  __shared__ __attribute__((aligned(16))) float bufB[XDIM * BT2]; // 64 KB
  __shared__ int   soff[N_ + 1];
  __shared__ int   sl160[E_];
  __shared__ int   sperm[N_];
  __shared__ float wts[160];
  const int t   = threadIdx.x;
  const int b0_ = blockIdx.x * BT2;

  for (int i = t; i < E_; i += NTG) sl160[i] = lst_g[i] * 160;
  if (t <= N_) soff[t] = off_g[t];
  if (t < N_) sperm[t] = perm_g[t];
  if (t < 5)  { wts[t] = W0[t]; wts[5 + t] = b0[t]; wts[35 + t] = gb0[t]; }
  if (t < 25) { wts[10 + t] = G0[t];
                wts[40 + t] = W1[t]; wts[70 + t]  = G1[t];
                wts[100 + t] = W2[t]; wts[130 + t] = G2[t]; }
  if (t < 5)  { wts[65 + t] = b1[t]; wts[95 + t]  = gb1[t];
                wts[125 + t] = b2[t]; wts[155 + t] = gb2[t]; }
  // coalesced input: 3200 contiguous floats, scatter into j=0 state slots
  for (int i = t; i < N_ * BT2; i += NTG) {
    int b = i / N_, n = i - b * N_;
    bufA[n * 160 + b] = data[(size_t)b0_ * N_ + i];
  }
  __syncthreads();

  // ---- Layer 0 (scalar input), vectorized over 4 batches/lane ----
  if (t < N_ * (BT2 / 4)) {
    const int nn = sperm[t >> 3];
    const int b4 = (t & 7) * 4;
    f32x4 a = (f32x4){0.f, 0.f, 0.f, 0.f};
    const int qe = soff[nn + 1];
    for (int q = soff[nn]; q < qe; ++q) a += *(const f32x4*)(bufA + sl160[q] + b4);
    f32x4 h2[5];
#pragma unroll
    for (int j = 0; j < 5; ++j) {
      float bb = wts[5 + j];
      h2[j] = a * wts[j] + (f32x4){bb, bb, bb, bb};
    }
#pragma unroll
    for (int j = 0; j < 5; ++j) {
      float gb = wts[35 + j];
      f32x4 g = (f32x4){gb, gb, gb, gb};
#pragma unroll
      for (int k = 0; k < 5; ++k) g += h2[k] * wts[10 + k * 5 + j];
      f32x4 o;
#pragma unroll
      for (int c = 0; c < 4; ++c) o[c] = leaky(sigm(g[c]) * h2[j][c]);
      *(f32x4*)(bufB + nn * 160 + j * 32 + b4) = o;
    }
  }
  __syncthreads();

  rgcn_layer(bufB, bufA, wts, soff, sl160, sperm, t, 40);    // layer 1: B -> A
  __syncthreads();
  rgcn_layer(bufA, bufB, wts, soff, sl160, sperm, t, 100);   // layer 2: A -> B
  __syncthreads();

  // transpose bufB[jn][b] -> bufA[b*513 + r] (write banks (b+r)%32: conflict-free)
  for (int i = t; i < BT2 * XWP; i += NTG) {
    int b = i & 31, r = i >> 5;
    bufA[b * 513 + r] = (r < XDIM) ? bufB[r * 32 + b] : 0.f;
  }
  __syncthreads();

  // fragment-ordered store: x-region = kchunks 0..15 of rowblks R0, R0+1.
  {
    const int R0 = blockIdx.x * 2;
    for (int i = t; i < 32 * 64; i += NTG) {   // 32 frags x 64 lanes
      int f = i >> 6, lane = i & 63;
      int h = f >> 4, kc = f & 15;
      int b = h * 16 + (lane & 15);
      int k0 = kc * 32 + (lane >> 4) * 8;
      const float* sp = bufA + b * 513 + k0;
      uint4 p;
      p.x = (unsigned)f2bf(sp[0]) | ((unsigned)f2bf(sp[1]) << 16);
      p.y = (unsigned)f2bf(sp[2]) | ((unsigned)f2bf(sp[3]) << 16);
      p.z = (unsigned)f2bf(sp[4]) | ((unsigned)f2bf(sp[5]) << 16);
      p.w = (unsigned)f2bf(sp[6]) | ((unsigned)f2bf(sp[7]) << 16);
      ((uint4*)awf)[((size_t)(R0 + h) * NKC + kc) * 64 + lane] = p;
    }
  }
}

// ---------------- Kernel D: split-K streaming MFMA GEMM1 ----------------------
// Fragment-ordered A/B: every load = 1KB lane-contiguous. MBG=32, KSPLIT=7
// (98 kchunks = 7 x 14), grid 1792 = 7 blocks/CU.
constexpr int MBG = 32;              // mlp_main rows per block
constexpr int MB2 = 16;              // tail_kernel rows per block
constexpr int EST = 136;
constexpr int KSPLIT = 7;
constexpr int SCC = 7;               // 64k-chunks per split (7 x 2 kchunks = 14)

__global__ __launch_bounds__(NT, 4) void mlp_main(
    const unsigned short* __restrict__ awf,
    const unsigned short* __restrict__ F1c, float* __restrict__ part)
{
  const int t     = threadIdx.x;
  const int rb    = blockIdx.x & 255;          // 8192/32 = 256 row-blocks
  const int split = blockIdx.x >> 8;           // 0..6
  const int row0  = rb * MBG;
  const int lane  = t & 63;
  const int w     = t >> 6;
  const int quad  = lane >> 4;
  const int ln    = lane & 15;
  const int kc0   = split * (2 * SCC);         // first kchunk of this split

  const unsigned short* a0p = awf + (((size_t)(rb * 2 + 0) * NKC + kc0) * 64 + lane) * 8;
  const unsigned short* a1p = awf + (((size_t)(rb * 2 + 1) * NKC + kc0) * 64 + lane) * 8;
  const unsigned short* b0p = F1c + (((size_t)(w * 2 + 0) * NKC + kc0) * 64 + lane) * 8;
  const unsigned short* b1p = F1c + (((size_t)(w * 2 + 1) * NKC + kc0) * 64 + lane) * 8;

#define LOADF(Ax, Bx, c)                                                       \
  {                                                                            \
    _Pragma("unroll")                                                          \
    for (int s_ = 0; s_ < 2; ++s_) {                                           \
      const int o_ = (2 * (c) + s_) * 512;                                     \
      Ax[s_][0] = *(const short8*)(a0p + o_);                                  \
      Ax[s_][1] = *(const short8*)(a1p + o_);                                  \
      Bx[s_][0] = *(const short8*)(b0p + o_);                                  \
      Bx[s_][1] = *(const short8*)(b1p + o_);                                  \
    }                                                                          \
  }

  f32x4 a00 = {0.f, 0.f, 0.f, 0.f};
  f32x4 a01 = {0.f, 0.f, 0.f, 0.f};
  f32x4 a10 = {0.f, 0.f, 0.f, 0.f};
  f32x4 a11 = {0.f, 0.f, 0.f, 0.f};
  short8 A0[2][2], A1[2][2], B0[2][2], B1[2][2];

  LOADF(A0, B0, 0)
  LOADF(A1, B1, 1)
  for (int c = 0; c < SCC; ++c) {
    if (c & 1) {
#pragma unroll
      for (int s = 0; s < 2; ++s) {
        a00 = __builtin_amdgcn_mfma_f32_16x16x32_bf16(A1[s][0], B1[s][0], a00, 0, 0, 0);
        a01 = __builtin_amdgcn_mfma_f32_16x16x32_bf16(A1[s][0], B1[s][1], a01, 0, 0, 0);
        a10 = __builtin_amdgcn_mfma_f32_16x16x32_bf16(A1[s][1], B1[s][0], a10, 0, 0, 0);
        a11 = __builtin_amdgcn_mfma_f32_16x16x32_bf16(A1[s][1], B1[s][1], a11, 0, 0, 0);
      }
      if (c + 2 < SCC) LOADF(A1, B1, c + 2)
    } else {
#pragma unroll
      for (int s = 0; s < 2; ++s) {
        a00 = __builtin_amdgcn_mfma_f32_16x16x32_bf16(A0[s][0], B0[s][0], a00, 0, 0, 0);
        a01 = __builtin_amdgcn_mfma_f32_16x16x32_bf16(A0[s][0], B0[s][1], a01, 0, 0, 0);
        a10 = __builtin_amdgcn_mfma_f32_16x16x32_bf16(A0[s][1], B0[s][0], a10, 0, 0, 0);
        a11 = __builtin_amdgcn_mfma_f32_16x16x32_bf16(A0[s][1], B0[s][1], a11, 0, 0, 0);
      }
      if (c + 2 < SCC) LOADF(A0, B0, c + 2)
    }
  }
#undef LOADF

  // store partials (pre-bias): quad-contiguous 64B segments
  const int col0 = w * 32 + ln;
  float* pp = part + ((size_t)split * B_ + row0) * H1;
#pragma unroll
  for (int r = 0; r < 4; ++r) {
    int m = quad * 4 + r;
    pp[m * H1 + col0]             = a00[r];
    pp[m * H1 + col0 + 16]        = a01[r];
    pp[(m + 16) * H1 + col0]      = a10[r];
    pp[(m + 16) * H1 + col0 + 16] = a11[r];
  }
}

// ---------------- Kernel E: partial-sum + fused MLP tail ----------------------
__global__ __launch_bounds__(NT) void tail_kernel(
    const float* __restrict__ part, const float* __restrict__ fb1,
    const unsigned short* __restrict__ F2T, const float* __restrict__ fb2,
    const unsigned short* __restrict__ F3T, const float* __restrict__ fb3,
    const float* __restrict__ F4, const float* __restrict__ fb4,
    float* __restrict__ out)
{
  __shared__ __attribute__((aligned(16))) unsigned short sH[MB2 * EST];
  __shared__ float sh3[MB2 * 68];

  const int t    = threadIdx.x;
  const int row0 = blockIdx.x * MB2;
  const int lane = t & 63;
  const int w    = t >> 6;
  const int quad = lane >> 4;
  const int ln   = lane & 15;
  const int q8   = quad * 8;
  constexpr size_t PS = (size_t)B_ * H1;

  // h1 = leaky(sum partials + fb1) -> sH
  for (int i = t; i < MB2 * H1; i += NT) {
    int m = i >> 7, col = i & 127;
    size_t off = (size_t)(row0 + m) * H1 + col;
    float v = fb1[col];
#pragma unroll
    for (int s = 0; s < KSPLIT; ++s) v += part[s * PS + off];
    sH[m * EST + col] = f2bf(leaky(v));
  }
  __syncthreads();

  const int col0 = w * 32 + ln;
  // h2 = leaky(h1 @ F2 + fb2)
  f32x4 a20 = {0.f, 0.f, 0.f, 0.f};
  f32x4 a21 = {0.f, 0.f, 0.f, 0.f};
  {
    const unsigned short* g2a = F2T + (size_t)col0 * H2 + q8;
    const unsigned short* g2b = g2a + (size_t)16 * H2;
#pragma unroll
    for (int s = 0; s < 4; ++s) {
      short8 b0f = *(const short8*)(g2a + s * 32);
      short8 b1f = *(const short8*)(g2b + s * 32);
      short8 af  = *(const short8*)(sH + ln * EST + s * 32 + q8);
      a20 = __builtin_amdgcn_mfma_f32_16x16x32_bf16(af, b0f, a20, 0, 0, 0);
      a21 = __builtin_amdgcn_mfma_f32_16x16x32_bf16(af, b1f, a21, 0, 0, 0);
    }
  }
  __syncthreads();
  {
    float bb0 = fb2[col0], bb1 = fb2[col0 + 16];
#pragma unroll
    for (int r = 0; r < 4; ++r) {
      int m = quad * 4 + r;
      sH[m * EST + col0]      = f2bf(leaky(a20[r] + bb0));
      sH[m * EST + col0 + 16] = f2bf(leaky(a21[r] + bb1));
    }
  }
  __syncthreads();

  // h3 = leaky(h2 @ F3 + fb3): N=64
  f32x4 a3 = {0.f, 0.f, 0.f, 0.f};
  {
    const unsigned short* g3 = F3T + (size_t)(w * 16 + ln) * H2 + q8;
#pragma unroll
    for (int s = 0; s < 4; ++s) {
      short8 bf = *(const short8*)(g3 + s * 32);
      short8 af = *(const short8*)(sH + ln * EST + s * 32 + q8);
      a3 = __builtin_amdgcn_mfma_f32_16x16x32_bf16(af, bf, a3, 0, 0, 0);
    }
  }
  {
    int col = w * 16 + ln;
    float bb = fb3[col];
#pragma unroll
    for (int r = 0; r < 4; ++r)
      sh3[(quad * 4 + r) * 68 + col] = leaky(a3[r] + bb);
  }
  __syncthreads();

  // out = sigmoid(h3 @ F4 + fb4)
  if (t < MB2 * HO) {
    int m = t >> 1, j = t & 1;
    float a = fb4[j];
#pragma unroll 8
    for (int k = 0; k < H3; ++k) a += sh3[m * 68 + k] * F4[k * HO + j];
    out[(size_t)(row0 + m) * HO + j] = sigm(a);
  }
}

// ---------------- launch ------------------------------------------------------
extern "C" void kernel_launch(void* const* d_in, const int* in_sizes, int n_in,
                              void* d_out, int out_size, void* d_ws, size_t ws_size,
                              hipStream_t stream) {
  const float* data = (const float*)d_in[0];
  const float* dmat = (const float*)d_in[1];
  const int*   src  = (const int*)d_in[2];
  const int*   dst  = (const int*)d_in[3];
  const float* W0 = (const float*)d_in[4];  const float* b0 = (const float*)d_in[5];
  const float* G0 = (const float*)d_in[6];  const float* gb0 = (const float*)d_in[7];
  const float* W1 = (const float*)d_in[8];  const float* b1 = (const float*)d_in[9];
  const float* G1 = (const float*)d_in[10]; const float* gb1 = (const float*)d_in[11];
  const float* W2 = (const float*)d_in[12]; const float* b2 = (const float*)d_in[13];
  const float* G2 = (const float*)d_in[14]; const float* gb2 = (const float*)d_in[15];
  const float* F1 = (const float*)d_in[16]; const float* fb1 = (const float*)d_in[17];
  const float* F2 = (const float*)d_in[18]; const float* fb2 = (const float*)d_in[19];
  const float* F3 = (const float*)d_in[20]; const float* fb3 = (const float*)d_in[21];
  const float* F4 = (const float*)d_in[22]; const float* fb4 = (const float*)d_in[23];
  float* out = (float*)d_out;

  unsigned short* awf = (unsigned short*)d_ws;          // 512*98*512 shorts (51.4 MB)
  unsigned short* F1c = awf + (size_t)B_ * KPAD;        // 8*98*512
  unsigned short* F2T = F1c + 128 * KPAD;               // 128*128
  unsigned short* F3T = F2T + 128 * 128;                // 64*128
  int* off_g = (int*)(F3T + 64 * 128);                  // 101 (pad 104)
  int* lst_g = off_g + 104;                             // 1600
  int* perm_g = lst_g + 1600;                           // 100 (pad 104)
  float* part = (float*)(perm_g + 104);                 // 7*8192*128 fp32 (29.4 MB)

  setup_kernel<<<1 + 320 + 512 * NDT, NT, 0, stream>>>(src, dst, off_g, lst_g, perm_g,
                                                       F1, F2, F3, F1c, F2T, F3T,
                                                       dmat, awf);
  gnn_kernel<<<B_ / BT2, NTG, 0, stream>>>(data, off_g, lst_g, perm_g,
                                           W0, b0, G0, gb0,
                                           W1, b1, G1, gb1,
                                           W2, b2, G2, gb2, awf);
  mlp_main<<<(B_ / MBG) * KSPLIT, NT, 0, stream>>>(awf, F1c, part);
  tail_kernel<<<B_ / MB2, NT, 0, stream>>>(part, fb1, F2T, fb2,
                                           F3T, fb3, F4, fb4, out);
}

// Round 9
// 232.757 us; speedup vs baseline: 1.6531x; 1.0132x over previous
//
#include <hip/hip_runtime.h>
#include <math.h>

#define NT 256
#define NTG 1024
constexpr int B_   = 8192;
constexpr int N_   = 100;
constexpr int E_   = 1600;
constexpr int EMB  = 5;
constexpr int XDIM = 500;    // N_*EMB
constexpr int DDIM = 2600;   // 50*52
constexpr int XWP  = 512;    // padded x-region width ([500,512) = 0)
constexpr int DOFF = 512;    // d-region start in k' space
constexpr int KPAD = 3136;   // k' = 98 kchunks of 32
constexpr int NKC  = 98;     // kchunks per row
constexpr int H1 = 128, H2 = 128, H3 = 64, HO = 2;

typedef short short8 __attribute__((ext_vector_type(8)));
typedef float f32x4  __attribute__((ext_vector_type(4)));

__device__ __forceinline__ float leaky(float v) { return v > 0.f ? v : 0.01f * v; }
__device__ __forceinline__ float sigm(float v)  { return 1.f / (1.f + __expf(-v)); }
__device__ __forceinline__ unsigned short f2bf(float f) {   // RNE fp32->bf16
  unsigned int x = __float_as_uint(f);
  return (unsigned short)((x + 0x7fffu + ((x >> 16) & 1u)) >> 16);
}

// Fragment layout (matches mfma_f32_16x16x32_bf16 operand needs):
//   frag(R, kc)[lane][e] = M[R*16 + (lane&15)][kc*32 + (lane>>4)*8 + e]
//   linear: buf[(R*NKC + kc)*512 + lane*8 + e]   (512 shorts = 1KB per frag)

// ---------------- Kernel A: fused setup (csr | prep | d->fragments) -----------
// blk 0: CSR + degree-sort perm; blk 1..98: F1c kc-tiles (coalesced LDS bounce);
// blk 99..226: F2T; blk 227..290: F3T; blk 291..3362: d fp32 -> bf16 fragments.
// All phases alias ONE LDS buffer (union) so d-blocks keep 8-block/CU occupancy.
constexpr int NDT = 6;                 // col-tiles per rowblk (5 full + 1 partial)

__global__ __launch_bounds__(NT) void setup_kernel(
    const int* __restrict__ src, const int* __restrict__ dst,
    int* __restrict__ off_g, int* __restrict__ lst_g, int* __restrict__ perm_g,
    const float* __restrict__ F1, const float* __restrict__ F2, const float* __restrict__ F3,
    unsigned short* __restrict__ F1c, unsigned short* __restrict__ F2T, unsigned short* __restrict__ F3T,
    const float* __restrict__ dmat, unsigned short* __restrict__ awf)
{
  __shared__ __attribute__((aligned(16))) unsigned char sbuf[16640];  // union
  const int blk = blockIdx.x;
  const int t   = threadIdx.x;

  if (blk == 0) {
    // ---- CSR (dst-sorted) + degree-descending node permutation ----
    int* cnt = (int*)sbuf;             // N_+1
    int* cur = cnt + N_ + 1;           // N_
    if (t <= N_) cnt[t] = 0;
    __syncthreads();
    for (int e = t; e < E_; e += NT) atomicAdd(&cnt[dst[e] + 1], 1);
    __syncthreads();
    if (t == 0) {
      int s = 0;
      for (int n = 0; n <= N_; ++n) { s += cnt[n]; cnt[n] = s; }
    }
    __syncthreads();
    if (t < N_) cur[t] = cnt[t];
    if (t <= N_) off_g[t] = cnt[t];
    // rank nodes by degree (desc, stable): similar-degree nodes share a wave
    if (t < N_) {
      int dn = cnt[t + 1] - cnt[t];
      int r = 0;
      for (int m = 0; m < N_; ++m) {
        int dm = cnt[m + 1] - cnt[m];
        r += (dm > dn) || (dm == dn && m < t);
      }
      perm_g[r] = t;
    }
    __syncthreads();
    for (int e = t; e < E_; e += NT) {
      int d = dst[e];
      int p = atomicAdd(&cur[d], 1);
      lst_g[p] = src[e];
    }
  } else if (blk <= 98) {
    // ---- F1 -> fragment-ordered F1c, one kchunk (32 k'-rows) per block ----
    float (*tf)[129] = (float(*)[129])sbuf;        // 32x129 fp32 (16.5 KB)
    const int kc = blk - 1;
    for (int i = t; i < 32 * 128; i += NT) {       // coalesced row-major load
      int r = i >> 7, c = i & 127;
      int kp = kc * 32 + r;                        // k' index
      float v = 0.f;
      if (kp < XDIM)                          v = F1[(size_t)kp * H1 + c];
      else if (kp >= DOFF && kp < DOFF + DDIM) v = F1[(size_t)(kp - 12) * H1 + c];
      tf[r][c] = v;
    }
    __syncthreads();
    for (int i = t; i < 8 * 64; i += NT) {         // 8 colblk frags x 64 lanes
      int cb = i >> 6, lane = i & 63;
      int col = cb * 16 + (lane & 15);
      int q = lane >> 4;
      uint4 p;
      p.x = (unsigned)f2bf(tf[q * 8 + 0][col]) | ((unsigned)f2bf(tf[q * 8 + 1][col]) << 16);
      p.y = (unsigned)f2bf(tf[q * 8 + 2][col]) | ((unsigned)f2bf(tf[q * 8 + 3][col]) << 16);
      p.z = (unsigned)f2bf(tf[q * 8 + 4][col]) | ((unsigned)f2bf(tf[q * 8 + 5][col]) << 16);
      p.w = (unsigned)f2bf(tf[q * 8 + 6][col]) | ((unsigned)f2bf(tf[q * 8 + 7][col]) << 16);
      ((uint4*)F1c)[((size_t)cb * NKC + kc) * 64 + lane] = p;
    }
  } else if (blk <= 226) {
    int n = blk - 99;
    if (t < 128) F2T[n * 128 + t] = f2bf(F2[(size_t)t * H2 + n]);
  } else if (blk <= 290) {
    int n = blk - 227;
    if (t < 128) F3T[n * 128 + t] = f2bf(F3[(size_t)t * H3 + n]);
  } else {
    // ---- d fp32 -> bf16 fragments: one (rowblk R, col-tile ct) per block ----
    const int idx = blk - 291;               // 0..3071
    const int R   = idx / NDT;               // 0..511 (16 rows each)
    const int ct  = idx - R * NDT;           // 0..5 (512 d-cols each; ct5 = 40)
    unsigned short (*tile)[520] = (unsigned short(*)[520])sbuf;  // 16x520 (16.6 KB)
    const float* dbase = dmat + (size_t)R * 16 * DDIM + ct * 512;

    if (ct < 5) {
      for (int i = t; i < 16 * 128; i += NT) {       // 2048 float4 loads
        int r = i >> 7, c4 = i & 127;
        float4 f = *(const float4*)(dbase + (size_t)r * DDIM + c4 * 4);
        unsigned short* tp = &tile[r][c4 * 4];       // truncate fp32->bf16
        tp[0] = (unsigned short)(__float_as_uint(f.x) >> 16);
        tp[1] = (unsigned short)(__float_as_uint(f.y) >> 16);
        tp[2] = (unsigned short)(__float_as_uint(f.z) >> 16);
        tp[3] = (unsigned short)(__float_as_uint(f.w) >> 16);
      }
      __syncthreads();
      for (int i = t; i < 16 * 64; i += NT) {        // 16 kchunks x 64 lanes
        int kcL = i >> 6, lane = i & 63;
        int r = lane & 15, q = lane >> 4;
        uint4 p = *(const uint4*)&tile[r][kcL * 32 + q * 8];
        ((uint4*)awf)[((size_t)R * NKC + 16 + ct * 16 + kcL) * 64 + lane] = p;
      }
    } else {
      for (int i = t; i < 16 * 520; i += NT) ((unsigned short*)tile)[i] = 0;
      __syncthreads();
      for (int i = t; i < 16 * 10; i += NT) {        // 40 cols = 10 float4/row
        int r = i / 10, c4 = i - r * 10;
        float4 f = *(const float4*)(dbase + (size_t)r * DDIM + c4 * 4);
        unsigned short* tp = &tile[r][c4 * 4];
        tp[0] = (unsigned short)(__float_as_uint(f.x) >> 16);
        tp[1] = (unsigned short)(__float_as_uint(f.y) >> 16);
        tp[2] = (unsigned short)(__float_as_uint(f.z) >> 16);
        tp[3] = (unsigned short)(__float_as_uint(f.w) >> 16);
      }
      __syncthreads();
      for (int i = t; i < 2 * 64; i += NT) {         // kc 96, 97 (zero-padded)
        int kcL = i >> 6, lane = i & 63;
        int r = lane & 15, q = lane >> 4;
        uint4 p = *(const uint4*)&tile[r][kcL * 32 + q * 8];
        ((uint4*)awf)[((size_t)R * NKC + 96 + kcL) * 64 + lane] = p;
      }
    }
  }
}

// ---------------- Kernel C: gated RGCN, batch-along-lanes ---------------------
// BT2=32 batches/block, 1024 threads, stride-160 state (bank-balanced gathers).
// Nodes processed in degree-sorted order (sperm) to cut wave divergence.
constexpr int BT2 = 32;

__device__ __forceinline__ void rgcn_layer(
    const float* __restrict__ RB, float* __restrict__ WB,
    const float* __restrict__ wts, const int* __restrict__ soff,
    const int* __restrict__ sl160, const int* __restrict__ sperm,
    int t, int wof)
{
  if (t < N_ * (BT2 / 4)) {                  // 800 items: (node-slot, batch-quad)
    const int nn = sperm[t >> 3];
    const int b4 = (t & 7) * 4;
    f32x4 a[5];
#pragma unroll
    for (int j = 0; j < 5; ++j) a[j] = (f32x4){0.f, 0.f, 0.f, 0.f};
    const int qe = soff[nn + 1];
    for (int q = soff[nn]; q < qe; ++q) {
      const float* base = RB + sl160[q] + b4;
#pragma unroll
      for (int j = 0; j < 5; ++j) a[j] += *(const f32x4*)(base + j * 32);
    }
    f32x4 h2[5];
#pragma unroll
    for (int j = 0; j < 5; ++j) {
      float bb = wts[wof + 25 + j];
      f32x4 v = (f32x4){bb, bb, bb, bb};
#pragma unroll
      for (int k = 0; k < 5; ++k) v += a[k] * wts[wof + k * 5 + j];
      h2[j] = v;
    }
#pragma unroll
    for (int j = 0; j < 5; ++j) {
      float gb = wts[wof + 55 + j];
      f32x4 g = (f32x4){gb, gb, gb, gb};
#pragma unroll
      for (int k = 0; k < 5; ++k) g += h2[k] * wts[wof + 30 + k * 5 + j];
      f32x4 o;
#pragma unroll
      for (int c = 0; c < 4; ++c) o[c] = leaky(sigm(g[c]) * h2[j][c]);
      *(f32x4*)(WB + nn * 160 + j * 32 + b4) = o;
    }
  }
}

__global__ __launch_bounds__(NTG) void gnn_kernel(
    const float* __restrict__ data,
    const int* __restrict__ off_g, const int* __restrict__ lst_g, const int* __restrict__ perm_g,
    const float* __restrict__ W0, const float* __restrict__ b0, const float* __restrict__ G0, const float* __restrict__ gb0,
    const float* __restrict__ W1, const float* __restrict__ b1, const float* __restrict__ G1, const float* __restrict__ gb1,
    const float* __restrict__ W2, const float* __restrict__ b2, const float* __restrict__ G2, const float* __restrict__ gb2,
    unsigned short* __restrict__ awf)
{
  __shared__ __attribute__((aligned(16))) float bufA[BT2 * 513];  // 65.7 KB
  __shared__ __attribute__((aligned(16))) float bufB[XDIM * BT2]; // 64 KB
  __shared__ int   soff[N_ + 1];
  __shared__ int   sl160[E_];
  __shared__ int   sperm[N_];
  __shared__ float wts[160];
  const int t   = threadIdx.x;
  const int b0_ = blockIdx.x * BT2;

  for (int i = t; i < E_; i += NTG) sl160[i] = lst_g[i] * 160;
  if (t <= N_) soff[t] = off_g[t];
  if (t < N_) sperm[t] = perm_g[t];
  if (t < 5)  { wts[t] = W0[t]; wts[5 + t] = b0[t]; wts[35 + t] = gb0[t]; }
  if (t < 25) { wts[10 + t] = G0[t];
                wts[40 + t] = W1[t]; wts[70 + t]  = G1[t];
                wts[100 + t] = W2[t]; wts[130 + t] = G2[t]; }
  if (t < 5)  { wts[65 + t] = b1[t]; wts[95 + t]  = gb1[t];
                wts[125 + t] = b2[t]; wts[155 + t] = gb2[t]; }
  // coalesced input: 3200 contiguous floats, scatter into j=0 state slots
  for (int i = t; i < N_ * BT2; i += NTG) {
    int b = i / N_, n = i - b * N_;
    bufA[n * 160 + b] = data[(size_t)b0_ * N_ + i];
  }
  __syncthreads();

  // ---- Layer 0 (scalar input), vectorized over 4 batches/lane ----
  if (t < N_ * (BT2 / 4)) {
    const int nn = sperm[t >> 3];
    const int b4 = (t & 7) * 4;
    f32x4 a = (f32x4){0.f, 0.f, 0.f, 0.f};
    const int qe = soff[nn + 1];
    for (int q = soff[nn]; q < qe; ++q) a += *(const f32x4*)(bufA + sl160[q] + b4);
    f32x4 h2[5];
#pragma unroll
    for (int j = 0; j < 5; ++j) {
      float bb = wts[5 + j];
      h2[j] = a * wts[j] + (f32x4){bb, bb, bb, bb};
    }
#pragma unroll
    for (int j = 0; j < 5; ++j) {
      float gb = wts[35 + j];
      f32x4 g = (f32x4){gb, gb, gb, gb};
#pragma unroll
      for (int k = 0; k < 5; ++k) g += h2[k] * wts[10 + k * 5 + j];
      f32x4 o;
#pragma unroll
      for (int c = 0; c < 4; ++c) o[c] = leaky(sigm(g[c]) * h2[j][c]);
      *(f32x4*)(bufB + nn * 160 + j * 32 + b4) = o;
    }
  }
  __syncthreads();

  rgcn_layer(bufB, bufA, wts, soff, sl160, sperm, t, 40);    // layer 1: B -> A
  __syncthreads();
  rgcn_layer(bufA, bufB, wts, soff, sl160, sperm, t, 100);   // layer 2: A -> B
  __syncthreads();

  // transpose bufB[jn][b] -> bufA[b*513 + r] (write banks (b+r)%32: conflict-free)
  for (int i = t; i < BT2 * XWP; i += NTG) {
    int b = i & 31, r = i >> 5;
    bufA[b * 513 + r] = (r < XDIM) ? bufB[r * 32 + b] : 0.f;
  }
  __syncthreads();

  // fragment-ordered store: x-region = kchunks 0..15 of rowblks R0, R0+1.
  {
    const int R0 = blockIdx.x * 2;
    for (int i = t; i < 32 * 64; i += NTG) {   // 32 frags x 64 lanes
      int f = i >> 6, lane = i & 63;
      int h = f >> 4, kc = f & 15;
      int b = h * 16 + (lane & 15);
      int k0 = kc * 32 + (lane >> 4) * 8;
      const float* sp = bufA + b * 513 + k0;
      uint4 p;
      p.x = (unsigned)f2bf(sp[0]) | ((unsigned)f2bf(sp[1]) << 16);
      p.y = (unsigned)f2bf(sp[2]) | ((unsigned)f2bf(sp[3]) << 16);
      p.z = (unsigned)f2bf(sp[4]) | ((unsigned)f2bf(sp[5]) << 16);
      p.w = (unsigned)f2bf(sp[6]) | ((unsigned)f2bf(sp[7]) << 16);
      ((uint4*)awf)[((size_t)(R0 + h) * NKC + kc) * 64 + lane] = p;
    }
  }
}

// ---------------- Kernel D: split-K streaming MFMA GEMM1 ----------------------
// Fragment-ordered A/B: every load = 1KB lane-contiguous. MBG=32, KSPLIT=7
// (98 kchunks = 7 x 14), grid 1792 = 7 blocks/CU.
constexpr int MBG = 32;              // mlp_main rows per block
constexpr int MB2 = 16;              // tail_kernel rows per block
constexpr int EST = 136;
constexpr int KSPLIT = 7;
constexpr int SCC = 7;               // 64k-chunks per split (7 x 2 kchunks = 14)

__global__ __launch_bounds__(NT, 4) void mlp_main(
    const unsigned short* __restrict__ awf,
    const unsigned short* __restrict__ F1c, float* __restrict__ part)
{
  const int t     = threadIdx.x;
  const int rb    = blockIdx.x & 255;          // 8192/32 = 256 row-blocks
  const int split = blockIdx.x >> 8;           // 0..6
  const int row0  = rb * MBG;
  const int lane  = t & 63;
  const int w     = t >> 6;
  const int quad  = lane >> 4;
  const int ln    = lane & 15;
  const int kc0   = split * (2 * SCC);         // first kchunk of this split

  const unsigned short* a0p = awf + (((size_t)(rb * 2 + 0) * NKC + kc0) * 64 + lane) * 8;
  const unsigned short* a1p = awf + (((size_t)(rb * 2 + 1) * NKC + kc0) * 64 + lane) * 8;
  const unsigned short* b0p = F1c + (((size_t)(w * 2 + 0) * NKC + kc0) * 64 + lane) * 8;
  const unsigned short* b1p = F1c + (((size_t)(w * 2 + 1) * NKC + kc0) * 64 + lane) * 8;

#define LOADF(Ax, Bx, c)                                                       \
  {                                                                            \
    _Pragma("unroll")                                                          \
    for (int s_ = 0; s_ < 2; ++s_) {                                           \
      const int o_ = (2 * (c) + s_) * 512;                                     \
      Ax[s_][0] = *(const short8*)(a0p + o_);                                  \
      Ax[s_][1] = *(const short8*)(a1p + o_);                                  \
      Bx[s_][0] = *(const short8*)(b0p + o_);                                  \
      Bx[s_][1] = *(const short8*)(b1p + o_);                                  \
    }                                                                          \
  }

  f32x4 a00 = {0.f, 0.f, 0.f, 0.f};
  f32x4 a01 = {0.f, 0.f, 0.f, 0.f};
  f32x4 a10 = {0.f, 0.f, 0.f, 0.f};
  f32x4 a11 = {0.f, 0.f, 0.f, 0.f};
  short8 A0[2][2], A1[2][2], B0[2][2], B1[2][2];

  LOADF(A0, B0, 0)
  LOADF(A1, B1, 1)
  for (int c = 0; c < SCC; ++c) {
    if (c & 1) {
#pragma unroll
      for (int s = 0; s < 2; ++s) {
        a00 = __builtin_amdgcn_mfma_f32_16x16x32_bf16(A1[s][0], B1[s][0], a00, 0, 0, 0);
        a01 = __builtin_amdgcn_mfma_f32_16x16x32_bf16(A1[s][0], B1[s][1], a01, 0, 0, 0);
        a10 = __builtin_amdgcn_mfma_f32_16x16x32_bf16(A1[s][1], B1[s][0], a10, 0, 0, 0);
        a11 = __builtin_amdgcn_mfma_f32_16x16x32_bf16(A1[s][1], B1[s][1], a11, 0, 0, 0);
      }
      if (c + 2 < SCC) LOADF(A1, B1, c + 2)
    } else {
#pragma unroll
      for (int s = 0; s < 2; ++s) {
        a00 = __builtin_amdgcn_mfma_f32_16x16x32_bf16(A0[s][0], B0[s][0], a00, 0, 0, 0);
        a01 = __builtin_amdgcn_mfma_f32_16x16x32_bf16(A0[s][0], B0[s][1], a01, 0, 0, 0);
        a10 = __builtin_amdgcn_mfma_f32_16x16x32_bf16(A0[s][1], B0[s][0], a10, 0, 0, 0);
        a11 = __builtin_amdgcn_mfma_f32_16x16x32_bf16(A0[s][1], B0[s][1], a11, 0, 0, 0);
      }
      if (c + 2 < SCC) LOADF(A0, B0, c + 2)
    }
  }
#undef LOADF

  // store partials (pre-bias): quad-contiguous 64B segments
  const int col0 = w * 32 + ln;
  float* pp = part + ((size_t)split * B_ + row0) * H1;
#pragma unroll
  for (int r = 0; r < 4; ++r) {
    int m = quad * 4 + r;
    pp[m * H1 + col0]             = a00[r];
    pp[m * H1 + col0 + 16]        = a01[r];
    pp[(m + 16) * H1 + col0]      = a10[r];
    pp[(m + 16) * H1 + col0 + 16] = a11[r];
  }
}

// ---------------- Kernel E: partial-sum + fused MLP tail ----------------------
__global__ __launch_bounds__(NT) void tail_kernel(
    const float* __restrict__ part, const float* __restrict__ fb1,
    const unsigned short* __restrict__ F2T, const float* __restrict__ fb2,
    const unsigned short* __restrict__ F3T, const float* __restrict__ fb3,
    const float* __restrict__ F4, const float* __restrict__ fb4,
    float* __restrict__ out)
{
  __shared__ __attribute__((aligned(16))) unsigned short sH[MB2 * EST];
  __shared__ float sh3[MB2 * 68];

  const int t    = threadIdx.x;
  const int row0 = blockIdx.x * MB2;
  const int lane = t & 63;
  const int w    = t >> 6;
  const int quad = lane >> 4;
  const int ln   = lane & 15;
  const int q8   = quad * 8;
  constexpr size_t PS = (size_t)B_ * H1;

  // h1 = leaky(sum partials + fb1) -> sH
  for (int i = t; i < MB2 * H1; i += NT) {
    int m = i >> 7, col = i & 127;
    size_t off = (size_t)(row0 + m) * H1 + col;
    float v = fb1[col];
#pragma unroll
    for (int s = 0; s < KSPLIT; ++s) v += part[s * PS + off];
    sH[m * EST + col] = f2bf(leaky(v));
  }
  __syncthreads();

  const int col0 = w * 32 + ln;
  // h2 = leaky(h1 @ F2 + fb2)
  f32x4 a20 = {0.f, 0.f, 0.f, 0.f};
  f32x4 a21 = {0.f, 0.f, 0.f, 0.f};
  {
    const unsigned short* g2a = F2T + (size_t)col0 * H2 + q8;
    const unsigned short* g2b = g2a + (size_t)16 * H2;
#pragma unroll
    for (int s = 0; s < 4; ++s) {
      short8 b0f = *(const short8*)(g2a + s * 32);
      short8 b1f = *(const short8*)(g2b + s * 32);
      short8 af  = *(const short8*)(sH + ln * EST + s * 32 + q8);
      a20 = __builtin_amdgcn_mfma_f32_16x16x32_bf16(af, b0f, a20, 0, 0, 0);
      a21 = __builtin_amdgcn_mfma_f32_16x16x32_bf16(af, b1f, a21, 0, 0, 0);
    }
  }
  __syncthreads();
  {
    float bb0 = fb2[col0], bb1 = fb2[col0 + 16];
#pragma unroll
    for (int r = 0; r < 4; ++r) {
      int m = quad * 4 + r;
      sH[m * EST + col0]      = f2bf(leaky(a20[r] + bb0));
      sH[m * EST + col0 + 16] = f2bf(leaky(a21[r] + bb1));
    }
  }
  __syncthreads();

  // h3 = leaky(h2 @ F3 + fb3): N=64
  f32x4 a3 = {0.f, 0.f, 0.f, 0.f};
  {
    const unsigned short* g3 = F3T + (size_t)(w * 16 + ln) * H2 + q8;
#pragma unroll
    for (int s = 0; s < 4; ++s) {
      short8 bf = *(const short8*)(g3 + s * 32);
      short8 af = *(const short8*)(sH + ln * EST + s * 32 + q8);
      a3 = __builtin_amdgcn_mfma_f32_16x16x32_bf16(af, bf, a3, 0, 0, 0);
    }
  }
  {
    int col = w * 16 + ln;
    float bb = fb3[col];
#pragma unroll
    for (int r = 0; r < 4; ++r)
      sh3[(quad * 4 + r) * 68 + col] = leaky(a3[r] + bb);
  }
  __syncthreads();

  // out = sigmoid(h3 @ F4 + fb4)
  if (t < MB2 * HO) {
    int m = t >> 1, j = t & 1;
    float a = fb4[j];
#pragma unroll 8
    for (int k = 0; k < H3; ++k) a += sh3[m * 68 + k] * F4[k * HO + j];
    out[(size_t)(row0 + m) * HO + j] = sigm(a);
  }
}

// ---------------- launch ------------------------------------------------------
extern "C" void kernel_launch(void* const* d_in, const int* in_sizes, int n_in,
                              void* d_out, int out_size, void* d_ws, size_t ws_size,
                              hipStream_t stream) {
  const float* data = (const float*)d_in[0];
  const float* dmat = (const float*)d_in[1];
  const int*   src  = (const int*)d_in[2];
  const int*   dst  = (const int*)d_in[3];
  const float* W0 = (const float*)d_in[4];  const float* b0 = (const float*)d_in[5];
  const float* G0 = (const float*)d_in[6];  const float* gb0 = (const float*)d_in[7];
  const float* W1 = (const float*)d_in[8];  const float* b1 = (const float*)d_in[9];
  const float* G1 = (const float*)d_in[10]; const float* gb1 = (const float*)d_in[11];
  const float* W2 = (const float*)d_in[12]; const float* b2 = (const float*)d_in[13];
  const float* G2 = (const float*)d_in[14]; const float* gb2 = (const float*)d_in[15];
  const float* F1 = (const float*)d_in[16]; const float* fb1 = (const float*)d_in[17];
  const float* F2 = (const float*)d_in[18]; const float* fb2 = (const float*)d_in[19];
  const float* F3 = (const float*)d_in[20]; const float* fb3 = (const float*)d_in[21];
  const float* F4 = (const float*)d_in[22]; const float* fb4 = (const float*)d_in[23];
  float* out = (float*)d_out;

  unsigned short* awf = (unsigned short*)d_ws;          // 512*98*512 shorts (51.4 MB)
  unsigned short* F1c = awf + (size_t)B_ * KPAD;        // 8*98*512
  unsigned short* F2T = F1c + 128 * KPAD;               // 128*128
  unsigned short* F3T = F2T + 128 * 128;                // 64*128
  int* off_g = (int*)(F3T + 64 * 128);                  // 101 (pad 104)
  int* lst_g = off_g + 104;                             // 1600
  int* perm_g = lst_g + 1600;                           // 100 (pad 104)
  float* part = (float*)(perm_g + 104);                 // 7*8192*128 fp32 (29.4 MB)

  setup_kernel<<<1 + 290 + 512 * NDT, NT, 0, stream>>>(src, dst, off_g, lst_g, perm_g,
                                                       F1, F2, F3, F1c, F2T, F3T,
                                                       dmat, awf);
  gnn_kernel<<<B_ / BT2, NTG, 0, stream>>>(data, off_g, lst_g, perm_g,
                                           W0, b0, G0, gb0,
                                           W1, b1, G1, gb1,
                                           W2, b2, G2, gb2, awf);
  mlp_main<<<(B_ / MBG) * KSPLIT, NT, 0, stream>>>(awf, F1c, part);
  tail_kernel<<<B_ / MB2, NT, 0, stream>>>(part, fb1, F2T, fb2,
                                           F3T, fb3, F4, fb4, out);
}